// Round 9
// baseline (899.623 us; speedup 1.0000x reference)
//
#include <hip/hip_runtime.h>
#include <hip/hip_bf16.h>
#include <math.h>

typedef __hip_bfloat16 bf16;

#define NUSER 20000
#define NITEM 20000
#define NTOT  40000
#define DD    128
#define HH    4
#define TT    5
#define MMEM  8
#define EUI   40000
#define ET    16000

#define MP_N  40064   // NTOT padded to 128
#define MP_H  20096   // 20000 padded to 128

typedef __attribute__((ext_vector_type(8))) short short8;
typedef __attribute__((ext_vector_type(4))) float f32x4;

__device__ __forceinline__ void gload16(const bf16* g, bf16* l){
  __builtin_amdgcn_global_load_lds(
      (const __attribute__((address_space(1))) unsigned int*)g,
      (__attribute__((address_space(3))) unsigned int*)l, 16, 0, 0);
}
__device__ __forceinline__ float bu2f_lo(unsigned u){ return __uint_as_float(u << 16); }
__device__ __forceinline__ float bu2f_hi(unsigned u){ return __uint_as_float(u & 0xffff0000u); }

// swizzle helpers for global_load_lds staging of 32-col bf16 tiles (stride 32)
__device__ __forceinline__ int stage_cg(int lane){
  return (((lane&3) ^ ((lane>>2)&3) ^ (lane>>4)) << 3);
}
__device__ __forceinline__ int read_pc8(int lm, int lq){
  return ((lq ^ (lm&3) ^ ((lm>>2)&3)) << 3);
}

// ================= generic MFMA bf16 GEMM (used for proj) =================
// C = act(A @ B^T + bias); A:[Mp x K] bf16 (pad rows zero); B:[N x K] bf16; K%32==0
// Ring-3 LDS pipeline: stage step i+2 while computing step i; counted vmcnt(4)
// (never 0 in-loop) + raw s_barrier — loads get ~2 phases to land.
// [verified passing: rounds 5,6]
__global__ __launch_bounds__(256) void k_mfma_gemm(
    const bf16* __restrict__ A, const bf16* __restrict__ B,
    const float* __restrict__ bias, float* __restrict__ C,
    long Astr, long Bstr, long biasStr, long Cstr,
    int ldc, int M, int K, int act, int accum)
{
  A += (size_t)blockIdx.z*Astr; B += (size_t)blockIdx.z*Bstr;
  if (bias) bias += (size_t)blockIdx.z*biasStr;
  C += (size_t)blockIdx.z*Cstr;
  __shared__ bf16 As[3][4096];
  __shared__ bf16 Bs[3][4096];
  int tid = threadIdx.x;
  int wave = tid >> 6, lane = tid & 63;
  int r0 = blockIdx.x * 128, c0 = blockIdx.y * 128;
  int wm = (wave >> 1) * 64, wn = (wave & 1) * 64;
  f32x4 acc[4][4];
  #pragma unroll
  for (int i=0;i<4;i++)
    #pragma unroll
    for (int j=0;j<4;j++) acc[i][j] = (f32x4){0.f,0.f,0.f,0.f};

  int rq = lane >> 2;
  int cg = stage_cg(lane);
  const bf16* Ag = A + (size_t)(r0 + wave*32 + rq)*K + cg;
  const bf16* Bg = B + (size_t)(c0 + wave*32 + rq)*K + cg;
  int lm = lane & 15, lq = lane >> 4;
  int pc8 = read_pc8(lm, lq);

  int ns = K >> 5;
  // prologue: stage step 0 -> ring0, step 1 -> ring1
  {
    bf16* dA = &As[0][wave*1024]; bf16* dB = &Bs[0][wave*1024];
    gload16(Ag,        dA); gload16(Ag + 16*K, dA + 512);
    gload16(Bg,        dB); gload16(Bg + 16*K, dB + 512);
  }
  if (ns > 1){
    bf16* dA = &As[1][wave*1024]; bf16* dB = &Bs[1][wave*1024];
    gload16(Ag + 32,        dA); gload16(Ag + 16*K + 32, dA + 512);
    gload16(Bg + 32,        dB); gload16(Bg + 16*K + 32, dB + 512);
    asm volatile("s_waitcnt vmcnt(4)" ::: "memory");
  } else {
    asm volatile("s_waitcnt vmcnt(0)" ::: "memory");
  }
  __builtin_amdgcn_s_barrier();

  int cur = 0, stg = 2;
  for (int i = 0; i < ns; i++){
    if (i + 2 < ns){
      int k2 = (i + 2) << 5;
      bf16* dA = &As[stg][wave*1024]; bf16* dB = &Bs[stg][wave*1024];
      gload16(Ag + k2,        dA); gload16(Ag + 16*K + k2, dA + 512);
      gload16(Bg + k2,        dB); gload16(Bg + 16*K + k2, dB + 512);
    }
    const bf16* Ard = &As[cur][(wm + lm)*32 + pc8];
    const bf16* Brd = &Bs[cur][(wn + lm)*32 + pc8];
    short8 af[4], bfv[4];
    #pragma unroll
    for (int ii=0;ii<4;ii++) af[ii]  = *(const short8*)(Ard + ii*16*32);
    #pragma unroll
    for (int j=0;j<4;j++)    bfv[j]  = *(const short8*)(Brd + j*16*32);
    #pragma unroll
    for (int ii=0;ii<4;ii++)
      #pragma unroll
      for (int j=0;j<4;j++)
        acc[ii][j] = __builtin_amdgcn_mfma_f32_16x16x32_bf16(af[ii], bfv[j], acc[ii][j], 0, 0, 0);
    if (i < ns - 1){
      if (i + 2 < ns) asm volatile("s_waitcnt vmcnt(4)" ::: "memory");
      else            asm volatile("s_waitcnt vmcnt(0)" ::: "memory");
      __builtin_amdgcn_s_barrier();
    }
    cur = (cur == 2) ? 0 : cur + 1;
    stg = (stg == 2) ? 0 : stg + 1;
  }
  #pragma unroll
  for (int i=0;i<4;i++){
    #pragma unroll
    for (int j=0;j<4;j++){
      int c = c0 + wn + j*16 + lm;
      #pragma unroll
      for (int rg=0; rg<4; rg++){
        int r = r0 + wm + i*16 + lq*4 + rg;
        if (r < M){
          float v = acc[i][j][rg];
          if (bias) v += bias[c];
          if (act==1) v = v>0.f ? v : expm1f(v);
          float* cp = &C[(size_t)r*ldc + c];
          if (accum) *cp += v; else *cp = v;
        }
      }
    }
  }
}

// ============ fc GEMM fused with attention dots, bf16 F output ============
// F[r, h*128+c] = (featb @ W^T); el/er[r,h] = sum_c F*al / F*ar
// grid (MP_N/128, 4 heads); A:[MP_N x 128] bf16; B:[512 x 128] bf16 (head h rows h*128..)
// K-loop upgraded to the verified ring-3 counted-vmcnt pipeline (k_mfma_gemm's
// loop with K=128, ns=4). Epilogue (attn dots, F store, redE) unchanged.
__global__ __launch_bounds__(256) void k_fc_gemm(
    const bf16* __restrict__ A, const bf16* __restrict__ B,
    bf16* __restrict__ Fb, const float* __restrict__ al, const float* __restrict__ ar,
    float* __restrict__ el, float* __restrict__ er, int M)
{
  __shared__ bf16 As[3][4096];
  __shared__ bf16 Bs[3][4096];
  __shared__ float redE[2][2][128];   // [el|er][wn-half][row]
  int tid = threadIdx.x;
  int wave = tid >> 6, lane = tid & 63;
  int h = blockIdx.y;
  int r0 = blockIdx.x * 128;
  int wm = (wave >> 1) * 64, wn = (wave & 1) * 64;
  f32x4 acc[4][4];
  #pragma unroll
  for (int i=0;i<4;i++)
    #pragma unroll
    for (int j=0;j<4;j++) acc[i][j] = (f32x4){0.f,0.f,0.f,0.f};

  int rq = lane >> 2;
  int cg = stage_cg(lane);
  const bf16* Ag = A + (size_t)(r0 + wave*32 + rq)*128 + cg;
  const bf16* Bg = B + (size_t)(h*128 + wave*32 + rq)*128 + cg;
  int lm = lane & 15, lq = lane >> 4;
  int pc8 = read_pc8(lm, lq);

  // prologue: stage k-step 0 -> ring0, step 1 -> ring1 (ns = 4)
  {
    bf16* dA = &As[0][wave*1024]; bf16* dB = &Bs[0][wave*1024];
    gload16(Ag,            dA); gload16(Ag + 16*128, dA + 512);
    gload16(Bg,            dB); gload16(Bg + 16*128, dB + 512);
  }
  {
    bf16* dA = &As[1][wave*1024]; bf16* dB = &Bs[1][wave*1024];
    gload16(Ag + 32,       dA); gload16(Ag + 16*128 + 32, dA + 512);
    gload16(Bg + 32,       dB); gload16(Bg + 16*128 + 32, dB + 512);
  }
  asm volatile("s_waitcnt vmcnt(4)" ::: "memory");
  __builtin_amdgcn_s_barrier();

  #pragma unroll
  for (int i = 0; i < 4; i++){
    if (i + 2 < 4){
      const int k2 = (i + 2) << 5;
      bf16* dA = &As[(i+2)%3][wave*1024]; bf16* dB = &Bs[(i+2)%3][wave*1024];
      gload16(Ag + k2,        dA); gload16(Ag + 16*128 + k2, dA + 512);
      gload16(Bg + k2,        dB); gload16(Bg + 16*128 + k2, dB + 512);
    }
    const bf16* Ard = &As[i%3][(wm + lm)*32 + pc8];
    const bf16* Brd = &Bs[i%3][(wn + lm)*32 + pc8];
    short8 af[4], bfv[4];
    #pragma unroll
    for (int ii=0;ii<4;ii++) af[ii]  = *(const short8*)(Ard + ii*16*32);
    #pragma unroll
    for (int j=0;j<4;j++)    bfv[j]  = *(const short8*)(Brd + j*16*32);
    #pragma unroll
    for (int ii=0;ii<4;ii++)
      #pragma unroll
      for (int j=0;j<4;j++)
        acc[ii][j] = __builtin_amdgcn_mfma_f32_16x16x32_bf16(af[ii], bfv[j], acc[ii][j], 0, 0, 0);
    if (i < 3){
      if (i + 2 < 4) asm volatile("s_waitcnt vmcnt(4)" ::: "memory");
      else           asm volatile("s_waitcnt vmcnt(0)" ::: "memory");
      __builtin_amdgcn_s_barrier();
    }
  }
  // attn dot partials + reductions
  float alv[4], arv[4];
  #pragma unroll
  for (int j=0;j<4;j++){
    int c = h*128 + wn + j*16 + lm;
    alv[j] = al[c]; arv[j] = ar[c];
  }
  int wnh = wave & 1;
  #pragma unroll
  for (int i=0;i<4;i++){
    #pragma unroll
    for (int rg=0; rg<4; rg++){
      float se = 0.f, sr = 0.f;
      #pragma unroll
      for (int j=0;j<4;j++){
        float v = acc[i][j][rg];
        se = fmaf(v, alv[j], se);
        sr = fmaf(v, arv[j], sr);
      }
      #pragma unroll
      for (int msk=1; msk<16; msk<<=1){
        se += __shfl_xor(se, msk);
        sr += __shfl_xor(sr, msk);
      }
      if (lm == 0){
        int rl = wm + i*16 + lq*4 + rg;
        redE[0][wnh][rl] = se;
        redE[1][wnh][rl] = sr;
      }
    }
  }
  // F store (bf16)
  #pragma unroll
  for (int i=0;i<4;i++){
    #pragma unroll
    for (int j=0;j<4;j++){
      int c = h*128 + wn + j*16 + lm;
      #pragma unroll
      for (int rg=0; rg<4; rg++){
        int r = r0 + wm + i*16 + lq*4 + rg;
        if (r < M) Fb[(size_t)r*512 + c] = __float2bfloat16(acc[i][j][rg]);
      }
    }
  }
  __syncthreads();
  if (tid < 128){
    int r = r0 + tid;
    if (r < M) el[(size_t)r*4 + h] = redE[0][0][tid] + redE[0][1][tid];
  } else {
    int t2 = tid - 128;
    int r = r0 + t2;
    if (r < M) er[(size_t)r*4 + h] = redE[1][0][t2] + redE[1][1][t2];
  }
}

// ====== memory GEMM v7 (round-6 verified, 894 µs): ring-3/BK=64 counted-vmcnt,
// 32-row waves, BM=64. [v8 64-row-wave rewrite failed deterministically twice —
// reverted; debug offline before retrying.]
// mode 0: Cb[r*128+o] = bf16(acc)   (rel: msg)
// mode 2: fout = lrelu(C[r,o] + acc) + trans[r,o]   (node + final fuse)
__global__ __launch_bounds__(256) void k_memgemm(
    const float* __restrict__ feat, const int* __restrict__ src,
    const float* __restrict__ coef, const bf16* __restrict__ B,
    float* __restrict__ C, bf16* __restrict__ Cb,
    const float* __restrict__ trans, float* __restrict__ fout,
    long srcStr, long coefStr, long Bstr, long CbStr,
    int Mvalid, int mode)
{
  __shared__ bf16 Af[64*136];       // stride 136 -> 2-way (free) bank aliasing
  __shared__ float cfS[8*64];       // [m][row]
  __shared__ bf16 Bs[3][2][4096];   // ring of 3 x BK=64 phase slots (48 KB)
  int t = blockIdx.y;
  const int*   srcT  = src ? src + (size_t)t*srcStr : nullptr;
  const float* coefT = coef + (size_t)t*coefStr;
  const bf16*  Bt    = B + (size_t)t*Bstr;
  int tid = threadIdx.x, wave = tid >> 6, lane = tid & 63;
  int r0 = blockIdx.x * 64;

  // ---- stage 64 feat rows (fp32 -> bf16), 4 threads per row, coalesced ----
  {
    int rL = tid >> 2, seg = tid & 3;
    int r = r0 + rL;
    bool valid = r < Mvalid;
    int s = valid ? (srcT ? srcT[r] : r) : 0;
    const float4* fp = (const float4*)(feat + (size_t)s*128 + seg*32);
    bf16* ap = Af + rL*136 + seg*32;
    #pragma unroll
    for (int q=0;q<8;q+=2){
      float4 v0 = fp[q], v1 = fp[q+1];
      *(__hip_bfloat162*)(ap + q*4)     = __float22bfloat162_rn(make_float2(v0.x, v0.y));
      *(__hip_bfloat162*)(ap + q*4 + 2) = __float22bfloat162_rn(make_float2(v0.z, v0.w));
      *(__hip_bfloat162*)(ap + q*4 + 4) = __float22bfloat162_rn(make_float2(v1.x, v1.y));
      *(__hip_bfloat162*)(ap + q*4 + 6) = __float22bfloat162_rn(make_float2(v1.z, v1.w));
    }
  }
  // ---- stage coef transposed: cfS[m][r] ----
  if (tid < 64){
    int r = r0 + tid;
    bool valid = r < Mvalid;
    #pragma unroll
    for (int m=0;m<8;m++)
      cfS[m*64 + tid] = valid ? coefT[(size_t)r*8 + m] : 0.f;
  }

  int rq = lane >> 2;
  int cg = stage_cg(lane);
  const bf16* Bg0 = Bt + (size_t)(wave*32 + rq)*1024 + cg;
  const bf16* Bg1 = Bt + (size_t)(wave*32 + 16 + rq)*1024 + cg;
  int wm = (wave >> 1) * 32, wn = (wave & 1) * 64;
  int lm = lane & 15, lq = lane >> 4;
  int pc8 = read_pc8(lm, lq);

  // ---- prologue: stage phases 0,1 (kk = 0..3) ----
  #pragma unroll
  for (int p0=0; p0<2; p0++){
    #pragma unroll
    for (int h=0; h<2; h++){
      int kk = p0*2 + h;
      bf16* d = &Bs[p0][h][wave*1024];
      gload16(Bg0 + kk*32, d);
      gload16(Bg1 + kk*32, d + 512);
    }
  }
  // drain Af/cfS ds_writes (lgkm) + phase-0's 4 loads (vmcnt(4): phase 1 in flight)
  asm volatile("s_waitcnt lgkmcnt(0) vmcnt(4)" ::: "memory");
  __builtin_amdgcn_s_barrier();

  // ---- A fragments LDS -> registers ONCE (reused for all m) ----
  short8 afr[4][2];
  #pragma unroll
  for (int ic=0; ic<4; ic++)
    #pragma unroll
    for (int i=0; i<2; i++)
      afr[ic][i] = *(const short8*)(Af + (size_t)(wm + i*16 + lm)*136 + ic*32 + lq*8);

  f32x4 accC[2][4];
  #pragma unroll
  for (int i=0;i<2;i++)
    #pragma unroll
    for (int j=0;j<4;j++) accC[i][j] = (f32x4){0.f,0.f,0.f,0.f};
  f32x4 accM[2][4];

  #pragma unroll
  for (int p = 0; p < 16; p++){
    // issue staging for phase p+2 (slot (p+2)%3 — not read until phase p+2)
    if (p + 2 < 16){
      #pragma unroll
      for (int h=0; h<2; h++){
        const int kk = (p+2)*2 + h;
        bf16* d = &Bs[(p+2)%3][h][wave*1024];
        gload16(Bg0 + kk*32, d);
        gload16(Bg1 + kk*32, d + 512);
      }
    }
    // compute phase p: kk = 2p, 2p+1
    #pragma unroll
    for (int h=0; h<2; h++){
      const int kk = p*2 + h;
      const int ic = kk & 3;
      const bf16* bb = &Bs[p%3][h][0];
      short8 bfv[4];
      #pragma unroll
      for (int j=0;j<4;j++)
        bfv[j] = *(const short8*)(bb + (wn + lm + j*16)*32 + pc8);
      if (ic == 0){
        #pragma unroll
        for (int i=0;i<2;i++)
          #pragma unroll
          for (int j=0;j<4;j++)
            accM[i][j] = __builtin_amdgcn_mfma_f32_16x16x32_bf16(afr[0][i], bfv[j],
                             (f32x4){0.f,0.f,0.f,0.f}, 0, 0, 0);
      } else {
        #pragma unroll
        for (int i=0;i<2;i++)
          #pragma unroll
          for (int j=0;j<4;j++)
            accM[i][j] = __builtin_amdgcn_mfma_f32_16x16x32_bf16(afr[ic][i], bfv[j], accM[i][j], 0, 0, 0);
      }
    }
    // fold coef at C side after each m (= 2 phases)
    if (p & 1){
      const int m = p >> 1;
      #pragma unroll
      for (int i=0;i<2;i++){
        f32x4 cf4 = *(const f32x4*)(cfS + m*64 + wm + i*16 + lq*4);
        #pragma unroll
        for (int j=0;j<4;j++)
          #pragma unroll
          for (int rg=0; rg<4; rg++)
            accC[i][j][rg] = fmaf(cf4[rg], accM[i][j][rg], accC[i][j][rg]);
      }
    }
    // counted wait + barrier: keep phase p+2's loads in flight, drain p+1's
    if (p < 15){
      if (p + 2 < 16) asm volatile("s_waitcnt vmcnt(4)" ::: "memory");
      else            asm volatile("s_waitcnt vmcnt(0)" ::: "memory");
      __builtin_amdgcn_s_barrier();
    }
  }

  // epilogue
  #pragma unroll
  for (int i=0;i<2;i++){
    #pragma unroll
    for (int j=0;j<4;j++){
      int c = wn + j*16 + lm;
      #pragma unroll
      for (int rg=0; rg<4; rg++){
        int r = r0 + wm + i*16 + lq*4 + rg;
        if (r < Mvalid){
          float v = accC[i][j][rg];
          if (mode == 0){
            Cb[(size_t)t*CbStr + (size_t)r*128 + c] = __float2bfloat16(v);
          } else {
            float x = C[(size_t)r*128 + c] + v;
            x = x>0.f ? x : 0.2f*x;
            fout[(size_t)r*128 + c] = x + trans[(size_t)r*128 + c];
          }
        }
      }
    }
  }
}

// ---------- fp32 -> bf16 with zero pad ----------
__global__ void k_f2b(const float* __restrict__ in, bf16* __restrict__ o, int nv, int nt){
  int i = blockIdx.x*256 + threadIdx.x;
  if (i < nt) o[i] = __float2bfloat16(i < nv ? in[i] : 0.f);
}

// ---------- repack Ww (M,Do,Di) -> B^T [Do x (M*Di)] bf16, per slice ----------
__global__ void k_repack(const float* __restrict__ in, bf16* __restrict__ o){
  int s = blockIdx.y;
  int g = blockIdx.x*256 + threadIdx.x;          // g = m*16384 + od*128 + i
  int m = g >> 14, od = (g >> 7) & 127, i = g & 127;
  o[(size_t)s*131072 + (size_t)od*1024 + m*128 + i] = __float2bfloat16(in[(size_t)s*131072 + g]);
}

// ---------- CSR build ----------
__global__ void k_hist(const int* __restrict__ dIdx, int* __restrict__ cnt, int E){
  int e = blockIdx.x*256+threadIdx.x;
  if (e<E) atomicAdd(&cnt[dIdx[e]], 1);
}

__global__ __launch_bounds__(1024) void k_scan(const int* __restrict__ in,
                                               int* __restrict__ out, int n){
  __shared__ int wsum[16];
  __shared__ int carry;
  int tidx = threadIdx.x, lane = tidx & 63, w = tidx >> 6;
  if (tidx == 0) carry = 0;
  __syncthreads();
  for (int base = 0; base < n; base += 1024){
    int i = base + tidx;
    int v = (i < n) ? in[i] : 0;
    int x = v;
    #pragma unroll
    for (int off = 1; off < 64; off <<= 1){
      int t = __shfl_up(x, off);
      if (lane >= off) x += t;
    }
    if (lane == 63) wsum[w] = x;
    __syncthreads();
    if (w == 0 && lane < 16){
      int t = wsum[lane];
      #pragma unroll
      for (int off=1; off<16; off<<=1){
        int u = __shfl_up(t, off, 16);
        if (lane >= off) t += u;
      }
      wsum[lane] = t;
    }
    __syncthreads();
    int woff = (w == 0) ? 0 : wsum[w-1];
    int excl = carry + woff + x - v;
    if (i < n) out[i] = excl;
    __syncthreads();
    if (tidx == 1023) carry = carry + wsum[15];
    __syncthreads();
  }
  if (tidx == 0) out[n] = carry;
}

__global__ void k_csr_scatter(const int* __restrict__ sIdx, const int* __restrict__ dIdx,
                              int sOff, const int* __restrict__ rowptr,
                              int* __restrict__ cursor, int* __restrict__ col, int E){
  int e = blockIdx.x*256+threadIdx.x; if (e>=E) return;
  int d = dIdx[e];
  int pos = rowptr[d] + atomicAdd(&cursor[d], 1);
  col[pos] = sIdx[e] + sOff;
}

__global__ void k_csr_scatter_eid(const int* __restrict__ dIdx, const int* __restrict__ rowptr,
                                  int* __restrict__ cursor, int* __restrict__ col, int E){
  int e = blockIdx.x*256+threadIdx.x; if (e>=E) return;
  int d = dIdx[e];
  int pos = rowptr[d] + atomicAdd(&cursor[d], 1);
  col[pos] = e;
}

// ------- fused GAT aggregation: online softmax + bf16 gather + rstb epilogue -------
// rstb[dl, c] = bf16(elu(softmax-weighted-sum + gb[c]))
__global__ __launch_bounds__(64) void k_gat_gather(
    const int* __restrict__ rowptr, const int* __restrict__ col,
    const float* __restrict__ el, const float* __restrict__ er,
    const bf16* __restrict__ Fb, const float* __restrict__ gb,
    bf16* __restrict__ rstb, int dOff)
{
  int dl = blockIdx.x;
  int lane = threadIdx.x;
  int h = lane >> 4;
  int off = (lane & 15) << 3;
  float erh = er[(size_t)(dl + dOff)*4 + h];
  float m = -INFINITY, den = 0.f;
  float acc[8];
  #pragma unroll
  for (int i=0;i<8;i++) acc[i]=0.f;
  int jb = rowptr[dl], je = rowptr[dl+1];
  for (int j=jb; j<je; j++){
    int s = col[j];
    float e = el[(size_t)s*4+h] + erh;
    e = e > 0.f ? e : 0.2f*e;
    float mn = fmaxf(m, e);
    float sc = __expf(m - mn);
    float wj = __expf(e - mn);
    den = den*sc + wj;
    m = mn;
    uint4 u = *(const uint4*)(Fb + (size_t)s*512 + h*128 + off);
    acc[0]=acc[0]*sc + wj*bu2f_lo(u.x); acc[1]=acc[1]*sc + wj*bu2f_hi(u.x);
    acc[2]=acc[2]*sc + wj*bu2f_lo(u.y); acc[3]=acc[3]*sc + wj*bu2f_hi(u.y);
    acc[4]=acc[4]*sc + wj*bu2f_lo(u.z); acc[5]=acc[5]*sc + wj*bu2f_hi(u.z);
    acc[6]=acc[6]*sc + wj*bu2f_lo(u.w); acc[7]=acc[7]*sc + wj*bu2f_hi(u.w);
  }
  float inv = den > 0.f ? 1.f/den : 0.f;
  int cb = h*128 + off;
  float x[8];
  #pragma unroll
  for (int q=0;q<8;q++){
    float v = acc[q]*inv + gb[cb+q];
    x[q] = v>0.f ? v : expm1f(v);
  }
  union { uint4 u; __hip_bfloat162 p[4]; } O;
  #pragma unroll
  for (int q=0;q<4;q++) O.p[q] = __float22bfloat162_rn(make_float2(x[2*q], x[2*q+1]));
  *(uint4*)(rstb + (size_t)dl*512 + cb) = O.u;
}

// ---------- coef / ncoef: lrelu(x @ Wc^T + bc), M=8 outputs ----------
// vectorized: float4 feat loads + transposed weight LDS (bitwise-identical FMA order)
__global__ void k_coef(const float* __restrict__ feat, const int* __restrict__ idx,
                       const float* __restrict__ Wc, const float* __restrict__ bc,
                       float* __restrict__ outc, int cnt){
  int t = blockIdx.y;
  __shared__ float wT[DD*MMEM];   // [d][m]
  __shared__ float bS[MMEM];
  for (int i=threadIdx.x;i<MMEM*DD;i+=128){
    int m = i >> 7, d = i & 127;
    wT[d*MMEM + m] = Wc[(size_t)t*MMEM*DD + i];
  }
  if (threadIdx.x < MMEM) bS[threadIdx.x] = bc[t*MMEM + threadIdx.x];
  __syncthreads();
  int e = blockIdx.x*128 + threadIdx.x; if (e >= cnt) return;
  int node = idx ? idx[(size_t)t*cnt + e] : e;
  float acc[MMEM];
  #pragma unroll
  for (int m=0;m<MMEM;m++) acc[m]=bS[m];
  const float4* fr = (const float4*)(feat + (size_t)node*DD);
  for (int d4=0; d4<32; d4++){
    float4 v = fr[d4];
    const float* w0 = wT + d4*4*MMEM;
    #pragma unroll
    for (int m=0;m<MMEM;m++) acc[m] = fmaf(v.x, w0[m], acc[m]);
    #pragma unroll
    for (int m=0;m<MMEM;m++) acc[m] = fmaf(v.y, w0[MMEM+m], acc[m]);
    #pragma unroll
    for (int m=0;m<MMEM;m++) acc[m] = fmaf(v.z, w0[2*MMEM+m], acc[m]);
    #pragma unroll
    for (int m=0;m<MMEM;m++) acc[m] = fmaf(v.w, w0[3*MMEM+m], acc[m]);
  }
  float* op = outc + ((size_t)t*cnt + e)*MMEM;
  #pragma unroll
  for (int m=0;m<MMEM;m++){ float v=acc[m]; op[m] = v>0.f ? v : 0.2f*v; }
}

// ---------- memory segment-sum gather (bf16 msg) ----------
__global__ void k_mem_gather(const int* __restrict__ rpT, const int* __restrict__ colT,
                             const bf16* __restrict__ msg, float* __restrict__ sAgg){
  int n = blockIdx.x*4 + (threadIdx.x >> 6);
  if (n >= NTOT) return;
  int lane = threadIdx.x & 63;
  int jb = rpT[n], je = rpT[n+1];
  float a0=0.f, a1=0.f;
  for (int j=jb;j<je;j++){
    unsigned u = ((const unsigned*)(msg + (size_t)colT[j]*128))[lane];
    a0 += bu2f_lo(u); a1 += bu2f_hi(u);
  }
  *(float2*)(sAgg + (size_t)n*128 + lane*2) = make_float2(a0, a1);
}

// ---------- memory LN ----------
__global__ void k_memln(const float* __restrict__ s, const int* __restrict__ rpT,
                        const float* __restrict__ lw, const float* __restrict__ lb,
                        const float* __restrict__ hb, float* __restrict__ outp){
  int n = blockIdx.x, lane = threadIdx.x;
  float c = fmaxf((float)(rpT[n+1]-rpT[n]), 1.f);
  float x1 = s[(size_t)n*128+lane]/c, x2 = s[(size_t)n*128+64+lane]/c;
  float t = x1+x2;
  #pragma unroll
  for (int off=32;off;off>>=1) t += __shfl_xor(t,off);
  float mu = t * (1.f/128.f);
  float d1=x1-mu, d2=x2-mu;
  float v = d1*d1+d2*d2;
  #pragma unroll
  for (int off=32;off;off>>=1) v += __shfl_xor(v,off);
  float r = rsqrtf(v*(1.f/128.f) + 1e-5f);
  outp[(size_t)n*128+lane]    = d1*r*lw[lane]    + lb[lane]    + hb[lane];
  outp[(size_t)n*128+64+lane] = d2*r*lw[64+lane] + lb[64+lane] + hb[64+lane];
}

// ---------- final LN over 384-wide concat ----------
__global__ void k_final_ln(const float* __restrict__ emb, const float* __restrict__ f1,
                           const float* __restrict__ f2, const float* __restrict__ w,
                           const float* __restrict__ b, float* __restrict__ out){
  int n = blockIdx.x, t = threadIdx.x;
  __shared__ float red[4];
  float x0 = emb[(size_t)n*128+t];
  float x1 = f1[(size_t)n*128+t];
  float x2 = f2[(size_t)n*128+t];
  float s = x0+x1+x2;
  #pragma unroll
  for (int off=32;off;off>>=1) s += __shfl_xor(s,off);
  if ((t&63)==0) red[t>>6] = s;
  __syncthreads();
  float mu = (red[0]+red[1]) * (1.f/384.f);
  float d0=x0-mu, d1=x1-mu, d2=x2-mu;
  float v = d0*d0+d1*d1+d2*d2;
  #pragma unroll
  for (int off=32;off;off>>=1) v += __shfl_xor(v,off);
  if ((t&63)==0) red[2+(t>>6)] = v;
  __syncthreads();
  float var = (red[2]+red[3]) * (1.f/384.f);
  float r = rsqrtf(var + 1e-5f);
  size_t o = (size_t)n*384;
  out[o+t]     = d0*r*w[t]     + b[t];
  out[o+128+t] = d1*r*w[128+t] + b[128+t];
  out[o+256+t] = d2*r*w[256+t] + b[256+t];
}

extern "C" void kernel_launch(void* const* d_in, const int* in_sizes, int n_in,
                              void* d_out, int out_size, void* d_ws, size_t ws_size,
                              hipStream_t stream)
{
  const float* emb   = (const float*)d_in[0];
  const float* fcW   = (const float*)d_in[1];
  const float* attl  = (const float*)d_in[2];
  const float* attr  = (const float*)d_in[3];
  const float* gbias = (const float*)d_in[4];
  const float* projW = (const float*)d_in[5];
  const float* projB = (const float*)d_in[6];
  const float* relWc = (const float*)d_in[7];
  const float* relbc = (const float*)d_in[8];
  const float* relWw = (const float*)d_in[9];
  const float* nodWc = (const float*)d_in[10];
  const float* nodbc = (const float*)d_in[11];
  const float* nodWw = (const float*)d_in[12];
  const float* hbias = (const float*)d_in[13];
  const float* mlnw  = (const float*)d_in[14];
  const float* mlnb  = (const float*)d_in[15];
  const float* flnw  = (const float*)d_in[16];
  const float* flnb  = (const float*)d_in[17];
  const int*  srcU  = (const int*)d_in[18];
  const int*  dstI  = (const int*)d_in[19];
  const int*  eSrc  = (const int*)d_in[20];
  const int*  eDst  = (const int*)d_in[21];
  float* out = (float*)d_out;

  char* wp = (char*)d_ws;
  auto alloc = [&](size_t bytes)->void* {
    void* p = (void*)wp; wp += (bytes + 511) & ~(size_t)511; return p;
  };
  float* feat1 = (float*)alloc((size_t)NTOT*DD*4);
  float* feat2 = (float*)alloc((size_t)NTOT*DD*4);
  float* Fbuf  = (float*)alloc((size_t)NTOT*512*4);         // overlay region (82 MB)
  float* rst   = (float*)alloc((size_t)NTOT*DD*2*4);        // sAgg + memO (41 MB)
  bf16*  rstb0 = (bf16*)alloc((size_t)2*MP_H*512*2);        // rstb dir0+dir1
  float* trans = (float*)alloc((size_t)NTOT*DD*4);
  float* elF   = (float*)alloc((size_t)NTOT*4*4);
  float* erF   = (float*)alloc((size_t)NTOT*4*4);
  int* rpA  = (int*)alloc((size_t)(NUSER+1)*4);
  int* colA = (int*)alloc((size_t)EUI*4);
  int* rpB  = (int*)alloc((size_t)(NITEM+1)*4);
  int* colB = (int*)alloc((size_t)EUI*4);
  int* icnt = (int*)alloc((size_t)20000*4);
  int* icur = (int*)alloc((size_t)20000*4);
  int* rpT  = (int*)alloc((size_t)(NTOT+1)*4);
  int* colT = (int*)alloc((size_t)TT*ET*4);
  int* cntT = (int*)alloc((size_t)NTOT*4);
  int* icurT= (int*)alloc((size_t)NTOT*4);
  bf16* featb  = (bf16*)alloc((size_t)MP_N*DD*2);
  bf16* fcWb   = (bf16*)alloc((size_t)4*512*DD*2);
  bf16* projWb = (bf16*)alloc((size_t)4*DD*512*2);
  bf16* relWwb = (bf16*)alloc((size_t)10*DD*1024*2);
  bf16* nodWwb = (bf16*)alloc((size_t)2*DD*1024*2);
  // overlays in Fbuf:
  bf16*  Fb     = (bf16*)Fbuf;                                    // NTOT*512 bf16 (41 MB)
  bf16*  msgBb  = (bf16*)((char*)Fbuf + (size_t)NTOT*512*2);      // 5*ET*128 bf16
  float* coefB  = (float*)((char*)msgBb + (size_t)TT*ET*128*2);   // 5*ET*8 fp32
  float* ncoefB = coefB + (size_t)TT*ET*8;                        // NTOT*8 fp32
  bf16*  rstb1  = rstb0 + (size_t)MP_H*512;
  float* sAgg   = rst;
  float* memO   = rst + (size_t)NTOT*DD;

  // ---- one-time: weight conversion/repack ----
  k_f2b<<<dim3((4*512*DD+255)/256),256,0,stream>>>(fcW, fcWb, 4*512*DD, 4*512*DD);
  k_f2b<<<dim3((4*DD*512+255)/256),256,0,stream>>>(projW, projWb, 4*DD*512, 4*DD*512);
  k_repack<<<dim3(512,10),256,0,stream>>>(relWw, relWwb);
  k_repack<<<dim3(512,2),256,0,stream>>>(nodWw, nodWwb);
  // zero rstb padding rows (re-poisoned every launch)
  hipMemsetAsync(rstb0 + (size_t)20000*512, 0, (size_t)(MP_H-20000)*512*2, stream);
  hipMemsetAsync(rstb1 + (size_t)20000*512, 0, (size_t)(MP_H-20000)*512*2, stream);

  // ---- one-time: CSR builds ----
  hipMemsetAsync(icnt, 0, 20000*4, stream);
  hipMemsetAsync(icur, 0, 20000*4, stream);
  k_hist<<<dim3((EUI+255)/256),256,0,stream>>>(srcU, icnt, EUI);
  k_scan<<<dim3(1),1024,0,stream>>>(icnt, rpA, NUSER);
  k_csr_scatter<<<dim3((EUI+255)/256),256,0,stream>>>(dstI, srcU, NUSER, rpA, icur, colA, EUI);
  hipMemsetAsync(icnt, 0, 20000*4, stream);
  hipMemsetAsync(icur, 0, 20000*4, stream);
  k_hist<<<dim3((EUI+255)/256),256,0,stream>>>(dstI, icnt, EUI);
  k_scan<<<dim3(1),1024,0,stream>>>(icnt, rpB, NITEM);
  k_csr_scatter<<<dim3((EUI+255)/256),256,0,stream>>>(srcU, dstI, 0, rpB, icur, colB, EUI);
  hipMemsetAsync(cntT, 0, NTOT*4, stream);
  hipMemsetAsync(icurT, 0, NTOT*4, stream);
  k_hist<<<dim3((TT*ET+255)/256),256,0,stream>>>(eDst, cntT, TT*ET);
  k_scan<<<dim3(1),1024,0,stream>>>(cntT, rpT, NTOT);
  k_csr_scatter_eid<<<dim3((TT*ET+255)/256),256,0,stream>>>(eDst, rpT, icurT, colT, TT*ET);

  const float* feats[3] = {emb, feat1, feat2};
  for (int l=0; l<2; l++){
    const float* fin  = feats[l];
    float* fout = (float*)feats[l+1];

    k_f2b<<<dim3((MP_N*DD+255)/256),256,0,stream>>>(fin, featb, NTOT*DD, MP_N*DD);

    for (int d=0; d<2; d++){
      // F = feat @ W^T fused with attn dots; bf16 F out
      k_fc_gemm<<<dim3(MP_N/128, 4),256,0,stream>>>(
          featb, fcWb + (size_t)(l*2+d)*512*DD, Fb,
          attl+(size_t)(l*2+d)*512, attr+(size_t)(l*2+d)*512, elF, erF, NTOT);
      int dOff = (d==0) ? 0 : NUSER;
      const int* rp  = (d==0) ? rpA : rpB;
      const int* col = (d==0) ? colA : colB;
      // gather fused with elu(rst+gbias) -> bf16
      k_gat_gather<<<dim3(20000),64,0,stream>>>(rp, col, elF, erF, Fb,
          gbias+(size_t)(l*2+d)*512, (d==0) ? rstb0 : rstb1, dOff);
    }
    // proj both directions in one dispatch: M=20000, N=128, K=512
    k_mfma_gemm<<<dim3(MP_H/128, 1, 2),256,0,stream>>>(
        rstb0, projWb + (size_t)(l*2)*DD*512, projB + (size_t)(l*2)*DD, trans,
        (long)MP_H*512, (long)DD*512, (long)DD, (long)20000*DD,
        DD, 20000, 512, 1, 0);

    // ---- memory layer ----
    k_coef<<<dim3((ET+127)/128, TT),128,0,stream>>>(fin, eDst,
        relWc+(size_t)l*TT*MMEM*DD, relbc+(size_t)l*TT*MMEM, coefB, ET);
    k_memgemm<<<dim3(ET/64, TT),256,0,stream>>>(
        fin, eSrc, coefB, relWwb + (size_t)l*TT*DD*1024,
        nullptr, msgBb, nullptr, nullptr,
        (long)ET, (long)ET*8, (long)DD*1024, (long)ET*128, ET, 0);
    k_mem_gather<<<dim3(NTOT/4),256,0,stream>>>(rpT, colT, msgBb, sAgg);
    k_memln<<<dim3(NTOT),64,0,stream>>>(sAgg, rpT, mlnw+(size_t)l*DD, mlnb+(size_t)l*DD,
                                        hbias+(size_t)l*DD, memO);
    k_coef<<<dim3((NTOT+127)/128, 1),128,0,stream>>>(fin, nullptr,
        nodWc+(size_t)l*MMEM*DD, nodbc+(size_t)l*MMEM, ncoefB, NTOT);
    // node memgemm fused with lrelu(memO+acc)+trans -> fout
    k_memgemm<<<dim3(MP_N/64, 1),256,0,stream>>>(
        fin, nullptr, ncoefB, nodWwb + (size_t)l*DD*1024,
        memO, nullptr, trans, fout,
        0, 0, 0, 0, NTOT, 2);
  }

  k_final_ln<<<dim3(NTOT),128,0,stream>>>(emb, feat1, feat2, flnw, flnb, out);
}

// Round 10
// 887.915 us; speedup vs baseline: 1.0132x; 1.0132x over previous
//
#include <hip/hip_runtime.h>
#include <hip/hip_bf16.h>
#include <math.h>

typedef __hip_bfloat16 bf16;

#define NUSER 20000
#define NITEM 20000
#define NTOT  40000
#define DD    128
#define HH    4
#define TT    5
#define MMEM  8
#define EUI   40000
#define ET    16000

#define MP_N  40064   // NTOT padded to 128
#define MP_H  20096   // 20000 padded to 128

typedef __attribute__((ext_vector_type(8))) short short8;
typedef __attribute__((ext_vector_type(4))) float f32x4;

__device__ __forceinline__ void gload16(const bf16* g, bf16* l){
  __builtin_amdgcn_global_load_lds(
      (const __attribute__((address_space(1))) unsigned int*)g,
      (__attribute__((address_space(3))) unsigned int*)l, 16, 0, 0);
}
__device__ __forceinline__ float bu2f_lo(unsigned u){ return __uint_as_float(u << 16); }
__device__ __forceinline__ float bu2f_hi(unsigned u){ return __uint_as_float(u & 0xffff0000u); }

// swizzle helpers for global_load_lds staging of 32-col bf16 tiles (stride 32)
__device__ __forceinline__ int stage_cg(int lane){
  return (((lane&3) ^ ((lane>>2)&3) ^ (lane>>4)) << 3);
}
__device__ __forceinline__ int read_pc8(int lm, int lq){
  return ((lq ^ (lm&3) ^ ((lm>>2)&3)) << 3);
}

// ================= generic MFMA bf16 GEMM (used for proj) =================
// C = act(A @ B^T + bias); A:[Mp x K] bf16 (pad rows zero); B:[N x K] bf16; K%32==0
// Ring-3 LDS pipeline: stage step i+2 while computing step i; counted vmcnt(4)
// (never 0 in-loop) + raw s_barrier — loads get ~2 phases to land.
// [verified passing: rounds 5,6,9]
__global__ __launch_bounds__(256) void k_mfma_gemm(
    const bf16* __restrict__ A, const bf16* __restrict__ B,
    const float* __restrict__ bias, float* __restrict__ C,
    long Astr, long Bstr, long biasStr, long Cstr,
    int ldc, int M, int K, int act, int accum)
{
  A += (size_t)blockIdx.z*Astr; B += (size_t)blockIdx.z*Bstr;
  if (bias) bias += (size_t)blockIdx.z*biasStr;
  C += (size_t)blockIdx.z*Cstr;
  __shared__ bf16 As[3][4096];
  __shared__ bf16 Bs[3][4096];
  int tid = threadIdx.x;
  int wave = tid >> 6, lane = tid & 63;
  int r0 = blockIdx.x * 128, c0 = blockIdx.y * 128;
  int wm = (wave >> 1) * 64, wn = (wave & 1) * 64;
  f32x4 acc[4][4];
  #pragma unroll
  for (int i=0;i<4;i++)
    #pragma unroll
    for (int j=0;j<4;j++) acc[i][j] = (f32x4){0.f,0.f,0.f,0.f};

  int rq = lane >> 2;
  int cg = stage_cg(lane);
  const bf16* Ag = A + (size_t)(r0 + wave*32 + rq)*K + cg;
  const bf16* Bg = B + (size_t)(c0 + wave*32 + rq)*K + cg;
  int lm = lane & 15, lq = lane >> 4;
  int pc8 = read_pc8(lm, lq);

  int ns = K >> 5;
  // prologue: stage step 0 -> ring0, step 1 -> ring1
  {
    bf16* dA = &As[0][wave*1024]; bf16* dB = &Bs[0][wave*1024];
    gload16(Ag,        dA); gload16(Ag + 16*K, dA + 512);
    gload16(Bg,        dB); gload16(Bg + 16*K, dB + 512);
  }
  if (ns > 1){
    bf16* dA = &As[1][wave*1024]; bf16* dB = &Bs[1][wave*1024];
    gload16(Ag + 32,        dA); gload16(Ag + 16*K + 32, dA + 512);
    gload16(Bg + 32,        dB); gload16(Bg + 16*K + 32, dB + 512);
    asm volatile("s_waitcnt vmcnt(4)" ::: "memory");
  } else {
    asm volatile("s_waitcnt vmcnt(0)" ::: "memory");
  }
  __builtin_amdgcn_s_barrier();

  int cur = 0, stg = 2;
  for (int i = 0; i < ns; i++){
    if (i + 2 < ns){
      int k2 = (i + 2) << 5;
      bf16* dA = &As[stg][wave*1024]; bf16* dB = &Bs[stg][wave*1024];
      gload16(Ag + k2,        dA); gload16(Ag + 16*K + k2, dA + 512);
      gload16(Bg + k2,        dB); gload16(Bg + 16*K + k2, dB + 512);
    }
    const bf16* Ard = &As[cur][(wm + lm)*32 + pc8];
    const bf16* Brd = &Bs[cur][(wn + lm)*32 + pc8];
    short8 af[4], bfv[4];
    #pragma unroll
    for (int ii=0;ii<4;ii++) af[ii]  = *(const short8*)(Ard + ii*16*32);
    #pragma unroll
    for (int j=0;j<4;j++)    bfv[j]  = *(const short8*)(Brd + j*16*32);
    #pragma unroll
    for (int ii=0;ii<4;ii++)
      #pragma unroll
      for (int j=0;j<4;j++)
        acc[ii][j] = __builtin_amdgcn_mfma_f32_16x16x32_bf16(af[ii], bfv[j], acc[ii][j], 0, 0, 0);
    if (i < ns - 1){
      if (i + 2 < ns) asm volatile("s_waitcnt vmcnt(4)" ::: "memory");
      else            asm volatile("s_waitcnt vmcnt(0)" ::: "memory");
      __builtin_amdgcn_s_barrier();
    }
    cur = (cur == 2) ? 0 : cur + 1;
    stg = (stg == 2) ? 0 : stg + 1;
  }
  #pragma unroll
  for (int i=0;i<4;i++){
    #pragma unroll
    for (int j=0;j<4;j++){
      int c = c0 + wn + j*16 + lm;
      #pragma unroll
      for (int rg=0; rg<4; rg++){
        int r = r0 + wm + i*16 + lq*4 + rg;
        if (r < M){
          float v = acc[i][j][rg];
          if (bias) v += bias[c];
          if (act==1) v = v>0.f ? v : expm1f(v);
          float* cp = &C[(size_t)r*ldc + c];
          if (accum) *cp += v; else *cp = v;
        }
      }
    }
  }
}

// ============ fc GEMM fused with attention dots, bf16 F output ============
// F[r, h*128+c] = (featb @ W^T); el/er[r,h] = sum_c F*al / F*ar
// grid (MP_N/128, 4 heads); A:[MP_N x 128] bf16; B:[512 x 128] bf16 (head h rows h*128..)
// Ring-3 K-loop (ns=4). [verified passing: round 9]
__global__ __launch_bounds__(256) void k_fc_gemm(
    const bf16* __restrict__ A, const bf16* __restrict__ B,
    bf16* __restrict__ Fb, const float* __restrict__ al, const float* __restrict__ ar,
    float* __restrict__ el, float* __restrict__ er, int M)
{
  __shared__ bf16 As[3][4096];
  __shared__ bf16 Bs[3][4096];
  __shared__ float redE[2][2][128];   // [el|er][wn-half][row]
  int tid = threadIdx.x;
  int wave = tid >> 6, lane = tid & 63;
  int h = blockIdx.y;
  int r0 = blockIdx.x * 128;
  int wm = (wave >> 1) * 64, wn = (wave & 1) * 64;
  f32x4 acc[4][4];
  #pragma unroll
  for (int i=0;i<4;i++)
    #pragma unroll
    for (int j=0;j<4;j++) acc[i][j] = (f32x4){0.f,0.f,0.f,0.f};

  int rq = lane >> 2;
  int cg = stage_cg(lane);
  const bf16* Ag = A + (size_t)(r0 + wave*32 + rq)*128 + cg;
  const bf16* Bg = B + (size_t)(h*128 + wave*32 + rq)*128 + cg;
  int lm = lane & 15, lq = lane >> 4;
  int pc8 = read_pc8(lm, lq);

  // prologue: stage k-step 0 -> ring0, step 1 -> ring1 (ns = 4)
  {
    bf16* dA = &As[0][wave*1024]; bf16* dB = &Bs[0][wave*1024];
    gload16(Ag,            dA); gload16(Ag + 16*128, dA + 512);
    gload16(Bg,            dB); gload16(Bg + 16*128, dB + 512);
  }
  {
    bf16* dA = &As[1][wave*1024]; bf16* dB = &Bs[1][wave*1024];
    gload16(Ag + 32,       dA); gload16(Ag + 16*128 + 32, dA + 512);
    gload16(Bg + 32,       dB); gload16(Bg + 16*128 + 32, dB + 512);
  }
  asm volatile("s_waitcnt vmcnt(4)" ::: "memory");
  __builtin_amdgcn_s_barrier();

  #pragma unroll
  for (int i = 0; i < 4; i++){
    if (i + 2 < 4){
      const int k2 = (i + 2) << 5;
      bf16* dA = &As[(i+2)%3][wave*1024]; bf16* dB = &Bs[(i+2)%3][wave*1024];
      gload16(Ag + k2,        dA); gload16(Ag + 16*128 + k2, dA + 512);
      gload16(Bg + k2,        dB); gload16(Bg + 16*128 + k2, dB + 512);
    }
    const bf16* Ard = &As[i%3][(wm + lm)*32 + pc8];
    const bf16* Brd = &Bs[i%3][(wn + lm)*32 + pc8];
    short8 af[4], bfv[4];
    #pragma unroll
    for (int ii=0;ii<4;ii++) af[ii]  = *(const short8*)(Ard + ii*16*32);
    #pragma unroll
    for (int j=0;j<4;j++)    bfv[j]  = *(const short8*)(Brd + j*16*32);
    #pragma unroll
    for (int ii=0;ii<4;ii++)
      #pragma unroll
      for (int j=0;j<4;j++)
        acc[ii][j] = __builtin_amdgcn_mfma_f32_16x16x32_bf16(af[ii], bfv[j], acc[ii][j], 0, 0, 0);
    if (i < 3){
      if (i + 2 < 4) asm volatile("s_waitcnt vmcnt(4)" ::: "memory");
      else           asm volatile("s_waitcnt vmcnt(0)" ::: "memory");
      __builtin_amdgcn_s_barrier();
    }
  }
  // attn dot partials + reductions
  float alv[4], arv[4];
  #pragma unroll
  for (int j=0;j<4;j++){
    int c = h*128 + wn + j*16 + lm;
    alv[j] = al[c]; arv[j] = ar[c];
  }
  int wnh = wave & 1;
  #pragma unroll
  for (int i=0;i<4;i++){
    #pragma unroll
    for (int rg=0; rg<4; rg++){
      float se = 0.f, sr = 0.f;
      #pragma unroll
      for (int j=0;j<4;j++){
        float v = acc[i][j][rg];
        se = fmaf(v, alv[j], se);
        sr = fmaf(v, arv[j], sr);
      }
      #pragma unroll
      for (int msk=1; msk<16; msk<<=1){
        se += __shfl_xor(se, msk);
        sr += __shfl_xor(sr, msk);
      }
      if (lm == 0){
        int rl = wm + i*16 + lq*4 + rg;
        redE[0][wnh][rl] = se;
        redE[1][wnh][rl] = sr;
      }
    }
  }
  // F store (bf16)
  #pragma unroll
  for (int i=0;i<4;i++){
    #pragma unroll
    for (int j=0;j<4;j++){
      int c = h*128 + wn + j*16 + lm;
      #pragma unroll
      for (int rg=0; rg<4; rg++){
        int r = r0 + wm + i*16 + lq*4 + rg;
        if (r < M) Fb[(size_t)r*512 + c] = __float2bfloat16(acc[i][j][rg]);
      }
    }
  }
  __syncthreads();
  if (tid < 128){
    int r = r0 + tid;
    if (r < M) el[(size_t)r*4 + h] = redE[0][0][tid] + redE[0][1][tid];
  } else {
    int t2 = tid - 128;
    int r = r0 + t2;
    if (r < M) er[(size_t)r*4 + h] = redE[1][0][t2] + redE[1][1][t2];
  }
}

// ====== memory GEMM v10: C[r,o] (+)= sum_m cf[r,m] * (feat[src[r]] . B[t][o, m*128..])
// BARRIER-FREE K-loop: each wave stages exactly the 64 B-rows [wn, wn+64) that it
// reads (rows duplicated across waves; 2x staging traffic but B is L2-hot), into a
// PRIVATE ring-3 slot. No cross-wave LDS dependency in the loop -> zero in-loop
// barriers; per-wave counted s_waitcnt vmcnt(8) (vmcnt retires in issue order, so
// outstanding<=8 after issuing kk+2 implies chunk kk's 4 loads landed). Waves slip
// freely; TLP (8 waves/CU) hides load latency instead of lockstep barriers.
// A tile + coef staged once (single barrier). Swizzle per 16-row group unchanged
// (stage_cg/read_pc8). Identical MFMA/fold order -> bit-identical numerics to v7.
// mode 0: Cb[r*128+o] = bf16(acc)   (rel: msg)
// mode 2: fout = lrelu(C[r,o] + acc) + trans[r,o]   (node + final fuse)
__global__ __launch_bounds__(256) void k_memgemm(
    const float* __restrict__ feat, const int* __restrict__ src,
    const float* __restrict__ coef, const bf16* __restrict__ B,
    float* __restrict__ C, bf16* __restrict__ Cb,
    const float* __restrict__ trans, float* __restrict__ fout,
    long srcStr, long coefStr, long Bstr, long CbStr,
    int Mvalid, int mode)
{
  __shared__ bf16 Af[64*136];       // stride 136 -> 2-way (free) bank aliasing
  __shared__ float cfS[8*64];       // [m][row]
  __shared__ bf16 Bs[3][4][2048];   // [ring][wave][4 groups x 16 rows x 32 k] (48 KB)
  int t = blockIdx.y;
  const int*   srcT  = src ? src + (size_t)t*srcStr : nullptr;
  const float* coefT = coef + (size_t)t*coefStr;
  const bf16*  Bt    = B + (size_t)t*Bstr;
  int tid = threadIdx.x, wave = tid >> 6, lane = tid & 63;
  int r0 = blockIdx.x * 64;

  // ---- stage 64 feat rows (fp32 -> bf16), 4 threads per row, coalesced ----
  {
    int rL = tid >> 2, seg = tid & 3;
    int r = r0 + rL;
    bool valid = r < Mvalid;
    int s = valid ? (srcT ? srcT[r] : r) : 0;
    const float4* fp = (const float4*)(feat + (size_t)s*128 + seg*32);
    bf16* ap = Af + rL*136 + seg*32;
    #pragma unroll
    for (int q=0;q<8;q+=2){
      float4 v0 = fp[q], v1 = fp[q+1];
      *(__hip_bfloat162*)(ap + q*4)     = __float22bfloat162_rn(make_float2(v0.x, v0.y));
      *(__hip_bfloat162*)(ap + q*4 + 2) = __float22bfloat162_rn(make_float2(v0.z, v0.w));
      *(__hip_bfloat162*)(ap + q*4 + 4) = __float22bfloat162_rn(make_float2(v1.x, v1.y));
      *(__hip_bfloat162*)(ap + q*4 + 6) = __float22bfloat162_rn(make_float2(v1.z, v1.w));
    }
  }
  // ---- stage coef transposed: cfS[m][r] ----
  if (tid < 64){
    int r = r0 + tid;
    bool valid = r < Mvalid;
    #pragma unroll
    for (int m=0;m<8;m++)
      cfS[m*64 + tid] = valid ? coefT[(size_t)r*8 + m] : 0.f;
  }

  int rq = lane >> 2;
  int cg = stage_cg(lane);
  int wm = (wave >> 1) * 32, wn = (wave & 1) * 64;
  int lm = lane & 15, lq = lane >> 4;
  int pc8 = read_pc8(lm, lq);

  // per-wave B base pointers for its own 64 rows [wn, wn+64), 4 groups of 16 rows
  const bf16* Bg0 = Bt + (size_t)(wn +  0 + rq)*1024 + cg;
  const bf16* Bg1 = Bt + (size_t)(wn + 16 + rq)*1024 + cg;
  const bf16* Bg2 = Bt + (size_t)(wn + 32 + rq)*1024 + cg;
  const bf16* Bg3 = Bt + (size_t)(wn + 48 + rq)*1024 + cg;

#define ISSUE_B(kk) do{                          \
    bf16* _d = &Bs[(kk)%3][wave][0];             \
    gload16(Bg0 + (kk)*32, _d);                  \
    gload16(Bg1 + (kk)*32, _d + 512);            \
    gload16(Bg2 + (kk)*32, _d + 1024);           \
    gload16(Bg3 + (kk)*32, _d + 1536);           \
  }while(0)

  // ---- prologue: issue chunks 0,1 into private ring slots (8 loads in flight) ----
  ISSUE_B(0);
  ISSUE_B(1);

  // one barrier: Af/cfS ds_writes visible to all waves (B needs no cross-wave sync)
  asm volatile("s_waitcnt lgkmcnt(0)" ::: "memory");
  __builtin_amdgcn_s_barrier();

  // ---- A fragments LDS -> registers ONCE (reused for all m) ----
  short8 afr[4][2];
  #pragma unroll
  for (int ic=0; ic<4; ic++)
    #pragma unroll
    for (int i=0; i<2; i++)
      afr[ic][i] = *(const short8*)(Af + (size_t)(wm + i*16 + lm)*136 + ic*32 + lq*8);

  f32x4 accC[2][4];
  #pragma unroll
  for (int i=0;i<2;i++)
    #pragma unroll
    for (int j=0;j<4;j++) accC[i][j] = (f32x4){0.f,0.f,0.f,0.f};
  f32x4 accM[2][4];

  #pragma unroll
  for (int kk = 0; kk < 32; kk++){
    if (kk + 2 < 32) ISSUE_B(kk+2);
    // per-wave counted wait: oldest 4 (chunk kk's) retired when outstanding <= 8
    if (kk + 2 < 32)      asm volatile("s_waitcnt vmcnt(8)" ::: "memory");
    else if (kk + 1 < 32) asm volatile("s_waitcnt vmcnt(4)" ::: "memory");
    else                  asm volatile("s_waitcnt vmcnt(0)" ::: "memory");
    const int ic = kk & 3;
    const bf16* bb = &Bs[kk%3][wave][0];
    short8 bfv[4];
    #pragma unroll
    for (int j=0;j<4;j++)
      bfv[j] = *(const short8*)(bb + j*512 + lm*32 + pc8);
    if (ic == 0){
      #pragma unroll
      for (int i=0;i<2;i++)
        #pragma unroll
        for (int j=0;j<4;j++)
          accM[i][j] = __builtin_amdgcn_mfma_f32_16x16x32_bf16(afr[0][i], bfv[j],
                           (f32x4){0.f,0.f,0.f,0.f}, 0, 0, 0);
    } else {
      #pragma unroll
      for (int i=0;i<2;i++)
        #pragma unroll
        for (int j=0;j<4;j++)
          accM[i][j] = __builtin_amdgcn_mfma_f32_16x16x32_bf16(afr[ic][i], bfv[j], accM[i][j], 0, 0, 0);
    }
    // fold coef at C side after each m (= 4 chunks)
    if (ic == 3){
      const int m = kk >> 2;
      #pragma unroll
      for (int i=0;i<2;i++){
        f32x4 cf4 = *(const f32x4*)(cfS + m*64 + wm + i*16 + lq*4);
        #pragma unroll
        for (int j=0;j<4;j++)
          #pragma unroll
          for (int rg=0; rg<4; rg++)
            accC[i][j][rg] = fmaf(cf4[rg], accM[i][j][rg], accC[i][j][rg]);
      }
    }
  }
#undef ISSUE_B

  // epilogue
  #pragma unroll
  for (int i=0;i<2;i++){
    #pragma unroll
    for (int j=0;j<4;j++){
      int c = wn + j*16 + lm;
      #pragma unroll
      for (int rg=0; rg<4; rg++){
        int r = r0 + wm + i*16 + lq*4 + rg;
        if (r < Mvalid){
          float v = accC[i][j][rg];
          if (mode == 0){
            Cb[(size_t)t*CbStr + (size_t)r*128 + c] = __float2bfloat16(v);
          } else {
            float x = C[(size_t)r*128 + c] + v;
            x = x>0.f ? x : 0.2f*x;
            fout[(size_t)r*128 + c] = x + trans[(size_t)r*128 + c];
          }
        }
      }
    }
  }
}

// ---------- fp32 -> bf16 with zero pad ----------
__global__ void k_f2b(const float* __restrict__ in, bf16* __restrict__ o, int nv, int nt){
  int i = blockIdx.x*256 + threadIdx.x;
  if (i < nt) o[i] = __float2bfloat16(i < nv ? in[i] : 0.f);
}

// ---------- repack Ww (M,Do,Di) -> B^T [Do x (M*Di)] bf16, per slice ----------
__global__ void k_repack(const float* __restrict__ in, bf16* __restrict__ o){
  int s = blockIdx.y;
  int g = blockIdx.x*256 + threadIdx.x;          // g = m*16384 + od*128 + i
  int m = g >> 14, od = (g >> 7) & 127, i = g & 127;
  o[(size_t)s*131072 + (size_t)od*1024 + m*128 + i] = __float2bfloat16(in[(size_t)s*131072 + g]);
}

// ---------- CSR build ----------
__global__ void k_hist(const int* __restrict__ dIdx, int* __restrict__ cnt, int E){
  int e = blockIdx.x*256+threadIdx.x;
  if (e<E) atomicAdd(&cnt[dIdx[e]], 1);
}

__global__ __launch_bounds__(1024) void k_scan(const int* __restrict__ in,
                                               int* __restrict__ out, int n){
  __shared__ int wsum[16];
  __shared__ int carry;
  int tidx = threadIdx.x, lane = tidx & 63, w = tidx >> 6;
  if (tidx == 0) carry = 0;
  __syncthreads();
  for (int base = 0; base < n; base += 1024){
    int i = base + tidx;
    int v = (i < n) ? in[i] : 0;
    int x = v;
    #pragma unroll
    for (int off = 1; off < 64; off <<= 1){
      int t = __shfl_up(x, off);
      if (lane >= off) x += t;
    }
    if (lane == 63) wsum[w] = x;
    __syncthreads();
    if (w == 0 && lane < 16){
      int t = wsum[lane];
      #pragma unroll
      for (int off=1; off<16; off<<=1){
        int u = __shfl_up(t, off, 16);
        if (lane >= off) t += u;
      }
      wsum[lane] = t;
    }
    __syncthreads();
    int woff = (w == 0) ? 0 : wsum[w-1];
    int excl = carry + woff + x - v;
    if (i < n) out[i] = excl;
    __syncthreads();
    if (tidx == 1023) carry = carry + wsum[15];
    __syncthreads();
  }
  if (tidx == 0) out[n] = carry;
}

__global__ void k_csr_scatter(const int* __restrict__ sIdx, const int* __restrict__ dIdx,
                              int sOff, const int* __restrict__ rowptr,
                              int* __restrict__ cursor, int* __restrict__ col, int E){
  int e = blockIdx.x*256+threadIdx.x; if (e>=E) return;
  int d = dIdx[e];
  int pos = rowptr[d] + atomicAdd(&cursor[d], 1);
  col[pos] = sIdx[e] + sOff;
}

__global__ void k_csr_scatter_eid(const int* __restrict__ dIdx, const int* __restrict__ rowptr,
                                  int* __restrict__ cursor, int* __restrict__ col, int E){
  int e = blockIdx.x*256+threadIdx.x; if (e>=E) return;
  int d = dIdx[e];
  int pos = rowptr[d] + atomicAdd(&cursor[d], 1);
  col[pos] = e;
}

// ------- fused GAT aggregation: online softmax + bf16 gather + rstb epilogue -------
// rstb[dl, c] = bf16(elu(softmax-weighted-sum + gb[c]))
__global__ __launch_bounds__(64) void k_gat_gather(
    const int* __restrict__ rowptr, const int* __restrict__ col,
    const float* __restrict__ el, const float* __restrict__ er,
    const bf16* __restrict__ Fb, const float* __restrict__ gb,
    bf16* __restrict__ rstb, int dOff)
{
  int dl = blockIdx.x;
  int lane = threadIdx.x;
  int h = lane >> 4;
  int off = (lane & 15) << 3;
  float erh = er[(size_t)(dl + dOff)*4 + h];
  float m = -INFINITY, den = 0.f;
  float acc[8];
  #pragma unroll
  for (int i=0;i<8;i++) acc[i]=0.f;
  int jb = rowptr[dl], je = rowptr[dl+1];
  for (int j=jb; j<je; j++){
    int s = col[j];
    float e = el[(size_t)s*4+h] + erh;
    e = e > 0.f ? e : 0.2f*e;
    float mn = fmaxf(m, e);
    float sc = __expf(m - mn);
    float wj = __expf(e - mn);
    den = den*sc + wj;
    m = mn;
    uint4 u = *(const uint4*)(Fb + (size_t)s*512 + h*128 + off);
    acc[0]=acc[0]*sc + wj*bu2f_lo(u.x); acc[1]=acc[1]*sc + wj*bu2f_hi(u.x);
    acc[2]=acc[2]*sc + wj*bu2f_lo(u.y); acc[3]=acc[3]*sc + wj*bu2f_hi(u.y);
    acc[4]=acc[4]*sc + wj*bu2f_lo(u.z); acc[5]=acc[5]*sc + wj*bu2f_hi(u.z);
    acc[6]=acc[6]*sc + wj*bu2f_lo(u.w); acc[7]=acc[7]*sc + wj*bu2f_hi(u.w);
  }
  float inv = den > 0.f ? 1.f/den : 0.f;
  int cb = h*128 + off;
  float x[8];
  #pragma unroll
  for (int q=0;q<8;q++){
    float v = acc[q]*inv + gb[cb+q];
    x[q] = v>0.f ? v : expm1f(v);
  }
  union { uint4 u; __hip_bfloat162 p[4]; } O;
  #pragma unroll
  for (int q=0;q<4;q++) O.p[q] = __float22bfloat162_rn(make_float2(x[2*q], x[2*q+1]));
  *(uint4*)(rstb + (size_t)dl*512 + cb) = O.u;
}

// ---------- coef / ncoef: lrelu(x @ Wc^T + bc), M=8 outputs ----------
// vectorized: float4 feat loads + transposed weight LDS (bitwise-identical FMA order)
__global__ void k_coef(const float* __restrict__ feat, const int* __restrict__ idx,
                       const float* __restrict__ Wc, const float* __restrict__ bc,
                       float* __restrict__ outc, int cnt){
  int t = blockIdx.y;
  __shared__ float wT[DD*MMEM];   // [d][m]
  __shared__ float bS[MMEM];
  for (int i=threadIdx.x;i<MMEM*DD;i+=128){
    int m = i >> 7, d = i & 127;
    wT[d*MMEM + m] = Wc[(size_t)t*MMEM*DD + i];
  }
  if (threadIdx.x < MMEM) bS[threadIdx.x] = bc[t*MMEM + threadIdx.x];
  __syncthreads();
  int e = blockIdx.x*128 + threadIdx.x; if (e >= cnt) return;
  int node = idx ? idx[(size_t)t*cnt + e] : e;
  float acc[MMEM];
  #pragma unroll
  for (int m=0;m<MMEM;m++) acc[m]=bS[m];
  const float4* fr = (const float4*)(feat + (size_t)node*DD);
  for (int d4=0; d4<32; d4++){
    float4 v = fr[d4];
    const float* w0 = wT + d4*4*MMEM;
    #pragma unroll
    for (int m=0;m<MMEM;m++) acc[m] = fmaf(v.x, w0[m], acc[m]);
    #pragma unroll
    for (int m=0;m<MMEM;m++) acc[m] = fmaf(v.y, w0[MMEM+m], acc[m]);
    #pragma unroll
    for (int m=0;m<MMEM;m++) acc[m] = fmaf(v.z, w0[2*MMEM+m], acc[m]);
    #pragma unroll
    for (int m=0;m<MMEM;m++) acc[m] = fmaf(v.w, w0[3*MMEM+m], acc[m]);
  }
  float* op = outc + ((size_t)t*cnt + e)*MMEM;
  #pragma unroll
  for (int m=0;m<MMEM;m++){ float v=acc[m]; op[m] = v>0.f ? v : 0.2f*v; }
}

// ---------- memory segment-sum gather (bf16 msg) ----------
__global__ void k_mem_gather(const int* __restrict__ rpT, const int* __restrict__ colT,
                             const bf16* __restrict__ msg, float* __restrict__ sAgg){
  int n = blockIdx.x*4 + (threadIdx.x >> 6);
  if (n >= NTOT) return;
  int lane = threadIdx.x & 63;
  int jb = rpT[n], je = rpT[n+1];
  float a0=0.f, a1=0.f;
  for (int j=jb;j<je;j++){
    unsigned u = ((const unsigned*)(msg + (size_t)colT[j]*128))[lane];
    a0 += bu2f_lo(u); a1 += bu2f_hi(u);
  }
  *(float2*)(sAgg + (size_t)n*128 + lane*2) = make_float2(a0, a1);
}

// ---------- memory LN ----------
__global__ void k_memln(const float* __restrict__ s, const int* __restrict__ rpT,
                        const float* __restrict__ lw, const float* __restrict__ lb,
                        const float* __restrict__ hb, float* __restrict__ outp){
  int n = blockIdx.x, lane = threadIdx.x;
  float c = fmaxf((float)(rpT[n+1]-rpT[n]), 1.f);
  float x1 = s[(size_t)n*128+lane]/c, x2 = s[(size_t)n*128+64+lane]/c;
  float t = x1+x2;
  #pragma unroll
  for (int off=32;off;off>>=1) t += __shfl_xor(t,off);
  float mu = t * (1.f/128.f);
  float d1=x1-mu, d2=x2-mu;
  float v = d1*d1+d2*d2;
  #pragma unroll
  for (int off=32;off;off>>=1) v += __shfl_xor(v,off);
  float r = rsqrtf(v*(1.f/128.f) + 1e-5f);
  outp[(size_t)n*128+lane]    = d1*r*lw[lane]    + lb[lane]    + hb[lane];
  outp[(size_t)n*128+64+lane] = d2*r*lw[64+lane] + lb[64+lane] + hb[64+lane];
}

// ---------- final LN over 384-wide concat ----------
__global__ void k_final_ln(const float* __restrict__ emb, const float* __restrict__ f1,
                           const float* __restrict__ f2, const float* __restrict__ w,
                           const float* __restrict__ b, float* __restrict__ out){
  int n = blockIdx.x, t = threadIdx.x;
  __shared__ float red[4];
  float x0 = emb[(size_t)n*128+t];
  float x1 = f1[(size_t)n*128+t];
  float x2 = f2[(size_t)n*128+t];
  float s = x0+x1+x2;
  #pragma unroll
  for (int off=32;off;off>>=1) s += __shfl_xor(s,off);
  if ((t&63)==0) red[t>>6] = s;
  __syncthreads();
  float mu = (red[0]+red[1]) * (1.f/384.f);
  float d0=x0-mu, d1=x1-mu, d2=x2-mu;
  float v = d0*d0+d1*d1+d2*d2;
  #pragma unroll
  for (int off=32;off;off>>=1) v += __shfl_xor(v,off);
  if ((t&63)==0) red[2+(t>>6)] = v;
  __syncthreads();
  float var = (red[2]+red[3]) * (1.f/384.f);
  float r = rsqrtf(var + 1e-5f);
  size_t o = (size_t)n*384;
  out[o+t]     = d0*r*w[t]     + b[t];
  out[o+128+t] = d1*r*w[128+t] + b[128+t];
  out[o+256+t] = d2*r*w[256+t] + b[256+t];
}

extern "C" void kernel_launch(void* const* d_in, const int* in_sizes, int n_in,
                              void* d_out, int out_size, void* d_ws, size_t ws_size,
                              hipStream_t stream)
{
  const float* emb   = (const float*)d_in[0];
  const float* fcW   = (const float*)d_in[1];
  const float* attl  = (const float*)d_in[2];
  const float* attr  = (const float*)d_in[3];
  const float* gbias = (const float*)d_in[4];
  const float* projW = (const float*)d_in[5];
  const float* projB = (const float*)d_in[6];
  const float* relWc = (const float*)d_in[7];
  const float* relbc = (const float*)d_in[8];
  const float* relWw = (const float*)d_in[9];
  const float* nodWc = (const float*)d_in[10];
  const float* nodbc = (const float*)d_in[11];
  const float* nodWw = (const float*)d_in[12];
  const float* hbias = (const float*)d_in[13];
  const float* mlnw  = (const float*)d_in[14];
  const float* mlnb  = (const float*)d_in[15];
  const float* flnw  = (const float*)d_in[16];
  const float* flnb  = (const float*)d_in[17];
  const int*  srcU  = (const int*)d_in[18];
  const int*  dstI  = (const int*)d_in[19];
  const int*  eSrc  = (const int*)d_in[20];
  const int*  eDst  = (const int*)d_in[21];
  float* out = (float*)d_out;

  char* wp = (char*)d_ws;
  auto alloc = [&](size_t bytes)->void* {
    void* p = (void*)wp; wp += (bytes + 511) & ~(size_t)511; return p;
  };
  float* feat1 = (float*)alloc((size_t)NTOT*DD*4);
  float* feat2 = (float*)alloc((size_t)NTOT*DD*4);
  float* Fbuf  = (float*)alloc((size_t)NTOT*512*4);         // overlay region (82 MB)
  float* rst   = (float*)alloc((size_t)NTOT*DD*2*4);        // sAgg + memO (41 MB)
  bf16*  rstb0 = (bf16*)alloc((size_t)2*MP_H*512*2);        // rstb dir0+dir1
  float* trans = (float*)alloc((size_t)NTOT*DD*4);
  float* elF   = (float*)alloc((size_t)NTOT*4*4);
  float* erF   = (float*)alloc((size_t)NTOT*4*4);
  int* rpA  = (int*)alloc((size_t)(NUSER+1)*4);
  int* colA = (int*)alloc((size_t)EUI*4);
  int* rpB  = (int*)alloc((size_t)(NITEM+1)*4);
  int* colB = (int*)alloc((size_t)EUI*4);
  int* icnt = (int*)alloc((size_t)20000*4);
  int* icur = (int*)alloc((size_t)20000*4);
  int* rpT  = (int*)alloc((size_t)(NTOT+1)*4);
  int* colT = (int*)alloc((size_t)TT*ET*4);
  int* cntT = (int*)alloc((size_t)NTOT*4);
  int* icurT= (int*)alloc((size_t)NTOT*4);
  bf16* featb  = (bf16*)alloc((size_t)MP_N*DD*2);
  bf16* fcWb   = (bf16*)alloc((size_t)4*512*DD*2);
  bf16* projWb = (bf16*)alloc((size_t)4*DD*512*2);
  bf16* relWwb = (bf16*)alloc((size_t)10*DD*1024*2);
  bf16* nodWwb = (bf16*)alloc((size_t)2*DD*1024*2);
  // overlays in Fbuf:
  bf16*  Fb     = (bf16*)Fbuf;                                    // NTOT*512 bf16 (41 MB)
  bf16*  msgBb  = (bf16*)((char*)Fbuf + (size_t)NTOT*512*2);      // 5*ET*128 bf16
  float* coefB  = (float*)((char*)msgBb + (size_t)TT*ET*128*2);   // 5*ET*8 fp32
  float* ncoefB = coefB + (size_t)TT*ET*8;                        // NTOT*8 fp32
  bf16*  rstb1  = rstb0 + (size_t)MP_H*512;
  float* sAgg   = rst;
  float* memO   = rst + (size_t)NTOT*DD;

  // ---- one-time: weight conversion/repack ----
  k_f2b<<<dim3((4*512*DD+255)/256),256,0,stream>>>(fcW, fcWb, 4*512*DD, 4*512*DD);
  k_f2b<<<dim3((4*DD*512+255)/256),256,0,stream>>>(projW, projWb, 4*DD*512, 4*DD*512);
  k_repack<<<dim3(512,10),256,0,stream>>>(relWw, relWwb);
  k_repack<<<dim3(512,2),256,0,stream>>>(nodWw, nodWwb);
  // zero rstb padding rows (re-poisoned every launch)
  hipMemsetAsync(rstb0 + (size_t)20000*512, 0, (size_t)(MP_H-20000)*512*2, stream);
  hipMemsetAsync(rstb1 + (size_t)20000*512, 0, (size_t)(MP_H-20000)*512*2, stream);

  // ---- one-time: CSR builds ----
  hipMemsetAsync(icnt, 0, 20000*4, stream);
  hipMemsetAsync(icur, 0, 20000*4, stream);
  k_hist<<<dim3((EUI+255)/256),256,0,stream>>>(srcU, icnt, EUI);
  k_scan<<<dim3(1),1024,0,stream>>>(icnt, rpA, NUSER);
  k_csr_scatter<<<dim3((EUI+255)/256),256,0,stream>>>(dstI, srcU, NUSER, rpA, icur, colA, EUI);
  hipMemsetAsync(icnt, 0, 20000*4, stream);
  hipMemsetAsync(icur, 0, 20000*4, stream);
  k_hist<<<dim3((EUI+255)/256),256,0,stream>>>(dstI, icnt, EUI);
  k_scan<<<dim3(1),1024,0,stream>>>(icnt, rpB, NITEM);
  k_csr_scatter<<<dim3((EUI+255)/256),256,0,stream>>>(srcU, dstI, 0, rpB, icur, colB, EUI);
  hipMemsetAsync(cntT, 0, NTOT*4, stream);
  hipMemsetAsync(icurT, 0, NTOT*4, stream);
  k_hist<<<dim3((TT*ET+255)/256),256,0,stream>>>(eDst, cntT, TT*ET);
  k_scan<<<dim3(1),1024,0,stream>>>(cntT, rpT, NTOT);
  k_csr_scatter_eid<<<dim3((TT*ET+255)/256),256,0,stream>>>(eDst, rpT, icurT, colT, TT*ET);

  const float* feats[3] = {emb, feat1, feat2};
  for (int l=0; l<2; l++){
    const float* fin  = feats[l];
    float* fout = (float*)feats[l+1];

    k_f2b<<<dim3((MP_N*DD+255)/256),256,0,stream>>>(fin, featb, NTOT*DD, MP_N*DD);

    for (int d=0; d<2; d++){
      // F = feat @ W^T fused with attn dots; bf16 F out
      k_fc_gemm<<<dim3(MP_N/128, 4),256,0,stream>>>(
          featb, fcWb + (size_t)(l*2+d)*512*DD, Fb,
          attl+(size_t)(l*2+d)*512, attr+(size_t)(l*2+d)*512, elF, erF, NTOT);
      int dOff = (d==0) ? 0 : NUSER;
      const int* rp  = (d==0) ? rpA : rpB;
      const int* col = (d==0) ? colA : colB;
      // gather fused with elu(rst+gbias) -> bf16
      k_gat_gather<<<dim3(20000),64,0,stream>>>(rp, col, elF, erF, Fb,
          gbias+(size_t)(l*2+d)*512, (d==0) ? rstb0 : rstb1, dOff);
    }
    // proj both directions in one dispatch: M=20000, N=128, K=512
    k_mfma_gemm<<<dim3(MP_H/128, 1, 2),256,0,stream>>>(
        rstb0, projWb + (size_t)(l*2)*DD*512, projB + (size_t)(l*2)*DD, trans,
        (long)MP_H*512, (long)DD*512, (long)DD, (long)20000*DD,
        DD, 20000, 512, 1, 0);

    // ---- memory layer ----
    k_coef<<<dim3((ET+127)/128, TT),128,0,stream>>>(fin, eDst,
        relWc+(size_t)l*TT*MMEM*DD, relbc+(size_t)l*TT*MMEM, coefB, ET);
    k_memgemm<<<dim3(ET/64, TT),256,0,stream>>>(
        fin, eSrc, coefB, relWwb + (size_t)l*TT*DD*1024,
        nullptr, msgBb, nullptr, nullptr,
        (long)ET, (long)ET*8, (long)DD*1024, (long)ET*128, ET, 0);
    k_mem_gather<<<dim3(NTOT/4),256,0,stream>>>(rpT, colT, msgBb, sAgg);
    k_memln<<<dim3(NTOT),64,0,stream>>>(sAgg, rpT, mlnw+(size_t)l*DD, mlnb+(size_t)l*DD,
                                        hbias+(size_t)l*DD, memO);
    k_coef<<<dim3((NTOT+127)/128, 1),128,0,stream>>>(fin, nullptr,
        nodWc+(size_t)l*MMEM*DD, nodbc+(size_t)l*MMEM, ncoefB, NTOT);
    // node memgemm fused with lrelu(memO+acc)+trans -> fout
    k_memgemm<<<dim3(MP_N/64, 1),256,0,stream>>>(
        fin, nullptr, ncoefB, nodWwb + (size_t)l*DD*1024,
        memO, nullptr, trans, fout,
        0, 0, 0, 0, NTOT, 2);
  }

  k_final_ln<<<dim3(NTOT),128,0,stream>>>(emb, feat1, feat2, flnw, flnb, out);
}

// Round 11
// 883.326 us; speedup vs baseline: 1.0184x; 1.0052x over previous
//
#include <hip/hip_runtime.h>
#include <hip/hip_bf16.h>
#include <math.h>

typedef __hip_bfloat16 bf16;

#define NUSER 20000
#define NITEM 20000
#define NTOT  40000
#define DD    128
#define HH    4
#define TT    5
#define MMEM  8
#define EUI   40000
#define ET    16000

#define MP_N  40064   // NTOT padded to 128
#define MP_H  20096   // 20000 padded to 128

typedef __attribute__((ext_vector_type(8))) short short8;
typedef __attribute__((ext_vector_type(4))) float f32x4;

__device__ __forceinline__ void gload16(const bf16* g, bf16* l){
  __builtin_amdgcn_global_load_lds(
      (const __attribute__((address_space(1))) unsigned int*)g,
      (__attribute__((address_space(3))) unsigned int*)l, 16, 0, 0);
}
__device__ __forceinline__ float bu2f_lo(unsigned u){ return __uint_as_float(u << 16); }
__device__ __forceinline__ float bu2f_hi(unsigned u){ return __uint_as_float(u & 0xffff0000u); }

// swizzle helpers for global_load_lds staging of 32-col bf16 tiles (stride 32)
__device__ __forceinline__ int stage_cg(int lane){
  return (((lane&3) ^ ((lane>>2)&3) ^ (lane>>4)) << 3);
}
__device__ __forceinline__ int read_pc8(int lm, int lq){
  return ((lq ^ (lm&3) ^ ((lm>>2)&3)) << 3);
}

// ================= generic MFMA bf16 GEMM (used for proj) =================
// C = act(A @ B^T + bias); A:[Mp x K] bf16 (pad rows zero); B:[N x K] bf16; K%32==0
// Ring-3 LDS pipeline: stage step i+2 while computing step i; counted vmcnt(4)
// (never 0 in-loop) + raw s_barrier — loads get ~2 phases to land.
// [verified passing: rounds 5,6,9,10]
__global__ __launch_bounds__(256) void k_mfma_gemm(
    const bf16* __restrict__ A, const bf16* __restrict__ B,
    const float* __restrict__ bias, float* __restrict__ C,
    long Astr, long Bstr, long biasStr, long Cstr,
    int ldc, int M, int K, int act, int accum)
{
  A += (size_t)blockIdx.z*Astr; B += (size_t)blockIdx.z*Bstr;
  if (bias) bias += (size_t)blockIdx.z*biasStr;
  C += (size_t)blockIdx.z*Cstr;
  __shared__ bf16 As[3][4096];
  __shared__ bf16 Bs[3][4096];
  int tid = threadIdx.x;
  int wave = tid >> 6, lane = tid & 63;
  int r0 = blockIdx.x * 128, c0 = blockIdx.y * 128;
  int wm = (wave >> 1) * 64, wn = (wave & 1) * 64;
  f32x4 acc[4][4];
  #pragma unroll
  for (int i=0;i<4;i++)
    #pragma unroll
    for (int j=0;j<4;j++) acc[i][j] = (f32x4){0.f,0.f,0.f,0.f};

  int rq = lane >> 2;
  int cg = stage_cg(lane);
  const bf16* Ag = A + (size_t)(r0 + wave*32 + rq)*K + cg;
  const bf16* Bg = B + (size_t)(c0 + wave*32 + rq)*K + cg;
  int lm = lane & 15, lq = lane >> 4;
  int pc8 = read_pc8(lm, lq);

  int ns = K >> 5;
  // prologue: stage step 0 -> ring0, step 1 -> ring1
  {
    bf16* dA = &As[0][wave*1024]; bf16* dB = &Bs[0][wave*1024];
    gload16(Ag,        dA); gload16(Ag + 16*K, dA + 512);
    gload16(Bg,        dB); gload16(Bg + 16*K, dB + 512);
  }
  if (ns > 1){
    bf16* dA = &As[1][wave*1024]; bf16* dB = &Bs[1][wave*1024];
    gload16(Ag + 32,        dA); gload16(Ag + 16*K + 32, dA + 512);
    gload16(Bg + 32,        dB); gload16(Bg + 16*K + 32, dB + 512);
    asm volatile("s_waitcnt vmcnt(4)" ::: "memory");
  } else {
    asm volatile("s_waitcnt vmcnt(0)" ::: "memory");
  }
  __builtin_amdgcn_s_barrier();

  int cur = 0, stg = 2;
  for (int i = 0; i < ns; i++){
    if (i + 2 < ns){
      int k2 = (i + 2) << 5;
      bf16* dA = &As[stg][wave*1024]; bf16* dB = &Bs[stg][wave*1024];
      gload16(Ag + k2,        dA); gload16(Ag + 16*K + k2, dA + 512);
      gload16(Bg + k2,        dB); gload16(Bg + 16*K + k2, dB + 512);
    }
    const bf16* Ard = &As[cur][(wm + lm)*32 + pc8];
    const bf16* Brd = &Bs[cur][(wn + lm)*32 + pc8];
    short8 af[4], bfv[4];
    #pragma unroll
    for (int ii=0;ii<4;ii++) af[ii]  = *(const short8*)(Ard + ii*16*32);
    #pragma unroll
    for (int j=0;j<4;j++)    bfv[j]  = *(const short8*)(Brd + j*16*32);
    #pragma unroll
    for (int ii=0;ii<4;ii++)
      #pragma unroll
      for (int j=0;j<4;j++)
        acc[ii][j] = __builtin_amdgcn_mfma_f32_16x16x32_bf16(af[ii], bfv[j], acc[ii][j], 0, 0, 0);
    if (i < ns - 1){
      if (i + 2 < ns) asm volatile("s_waitcnt vmcnt(4)" ::: "memory");
      else            asm volatile("s_waitcnt vmcnt(0)" ::: "memory");
      __builtin_amdgcn_s_barrier();
    }
    cur = (cur == 2) ? 0 : cur + 1;
    stg = (stg == 2) ? 0 : stg + 1;
  }
  #pragma unroll
  for (int i=0;i<4;i++){
    #pragma unroll
    for (int j=0;j<4;j++){
      int c = c0 + wn + j*16 + lm;
      #pragma unroll
      for (int rg=0; rg<4; rg++){
        int r = r0 + wm + i*16 + lq*4 + rg;
        if (r < M){
          float v = acc[i][j][rg];
          if (bias) v += bias[c];
          if (act==1) v = v>0.f ? v : expm1f(v);
          float* cp = &C[(size_t)r*ldc + c];
          if (accum) *cp += v; else *cp = v;
        }
      }
    }
  }
}

// ============ fc GEMM fused with attention dots, bf16 F output ============
// F[r, h*128+c] = (featb @ W^T); el/er[r,h] = sum_c F*al / F*ar
// grid (MP_N/128, 4 heads); A:[MP_N x 128] bf16; B:[512 x 128] bf16 (head h rows h*128..)
// Ring-3 K-loop (ns=4). [verified passing: rounds 9,10]
__global__ __launch_bounds__(256) void k_fc_gemm(
    const bf16* __restrict__ A, const bf16* __restrict__ B,
    bf16* __restrict__ Fb, const float* __restrict__ al, const float* __restrict__ ar,
    float* __restrict__ el, float* __restrict__ er, int M)
{
  __shared__ bf16 As[3][4096];
  __shared__ bf16 Bs[3][4096];
  __shared__ float redE[2][2][128];   // [el|er][wn-half][row]
  int tid = threadIdx.x;
  int wave = tid >> 6, lane = tid & 63;
  int h = blockIdx.y;
  int r0 = blockIdx.x * 128;
  int wm = (wave >> 1) * 64, wn = (wave & 1) * 64;
  f32x4 acc[4][4];
  #pragma unroll
  for (int i=0;i<4;i++)
    #pragma unroll
    for (int j=0;j<4;j++) acc[i][j] = (f32x4){0.f,0.f,0.f,0.f};

  int rq = lane >> 2;
  int cg = stage_cg(lane);
  const bf16* Ag = A + (size_t)(r0 + wave*32 + rq)*128 + cg;
  const bf16* Bg = B + (size_t)(h*128 + wave*32 + rq)*128 + cg;
  int lm = lane & 15, lq = lane >> 4;
  int pc8 = read_pc8(lm, lq);

  // prologue: stage k-step 0 -> ring0, step 1 -> ring1 (ns = 4)
  {
    bf16* dA = &As[0][wave*1024]; bf16* dB = &Bs[0][wave*1024];
    gload16(Ag,            dA); gload16(Ag + 16*128, dA + 512);
    gload16(Bg,            dB); gload16(Bg + 16*128, dB + 512);
  }
  {
    bf16* dA = &As[1][wave*1024]; bf16* dB = &Bs[1][wave*1024];
    gload16(Ag + 32,       dA); gload16(Ag + 16*128 + 32, dA + 512);
    gload16(Bg + 32,       dB); gload16(Bg + 16*128 + 32, dB + 512);
  }
  asm volatile("s_waitcnt vmcnt(4)" ::: "memory");
  __builtin_amdgcn_s_barrier();

  #pragma unroll
  for (int i = 0; i < 4; i++){
    if (i + 2 < 4){
      const int k2 = (i + 2) << 5;
      bf16* dA = &As[(i+2)%3][wave*1024]; bf16* dB = &Bs[(i+2)%3][wave*1024];
      gload16(Ag + k2,        dA); gload16(Ag + 16*128 + k2, dA + 512);
      gload16(Bg + k2,        dB); gload16(Bg + 16*128 + k2, dB + 512);
    }
    const bf16* Ard = &As[i%3][(wm + lm)*32 + pc8];
    const bf16* Brd = &Bs[i%3][(wn + lm)*32 + pc8];
    short8 af[4], bfv[4];
    #pragma unroll
    for (int ii=0;ii<4;ii++) af[ii]  = *(const short8*)(Ard + ii*16*32);
    #pragma unroll
    for (int j=0;j<4;j++)    bfv[j]  = *(const short8*)(Brd + j*16*32);
    #pragma unroll
    for (int ii=0;ii<4;ii++)
      #pragma unroll
      for (int j=0;j<4;j++)
        acc[ii][j] = __builtin_amdgcn_mfma_f32_16x16x32_bf16(af[ii], bfv[j], acc[ii][j], 0, 0, 0);
    if (i < 3){
      if (i + 2 < 4) asm volatile("s_waitcnt vmcnt(4)" ::: "memory");
      else           asm volatile("s_waitcnt vmcnt(0)" ::: "memory");
      __builtin_amdgcn_s_barrier();
    }
  }
  // attn dot partials + reductions
  float alv[4], arv[4];
  #pragma unroll
  for (int j=0;j<4;j++){
    int c = h*128 + wn + j*16 + lm;
    alv[j] = al[c]; arv[j] = ar[c];
  }
  int wnh = wave & 1;
  #pragma unroll
  for (int i=0;i<4;i++){
    #pragma unroll
    for (int rg=0; rg<4; rg++){
      float se = 0.f, sr = 0.f;
      #pragma unroll
      for (int j=0;j<4;j++){
        float v = acc[i][j][rg];
        se = fmaf(v, alv[j], se);
        sr = fmaf(v, arv[j], sr);
      }
      #pragma unroll
      for (int msk=1; msk<16; msk<<=1){
        se += __shfl_xor(se, msk);
        sr += __shfl_xor(sr, msk);
      }
      if (lm == 0){
        int rl = wm + i*16 + lq*4 + rg;
        redE[0][wnh][rl] = se;
        redE[1][wnh][rl] = sr;
      }
    }
  }
  // F store (bf16)
  #pragma unroll
  for (int i=0;i<4;i++){
    #pragma unroll
    for (int j=0;j<4;j++){
      int c = h*128 + wn + j*16 + lm;
      #pragma unroll
      for (int rg=0; rg<4; rg++){
        int r = r0 + wm + i*16 + lq*4 + rg;
        if (r < M) Fb[(size_t)r*512 + c] = __float2bfloat16(acc[i][j][rg]);
      }
    }
  }
  __syncthreads();
  if (tid < 128){
    int r = r0 + tid;
    if (r < M) el[(size_t)r*4 + h] = redE[0][0][tid] + redE[0][1][tid];
  } else {
    int t2 = tid - 128;
    int r = r0 + t2;
    if (r < M) er[(size_t)r*4 + h] = redE[1][0][t2] + redE[1][1][t2];
  }
}

// ====== memory GEMM v11: C[r,o] (+)= sum_m cf[r,m] * (feat[src[r]] . B[t][o, m*128..])
// v10 barrier-free private-ring structure + CHUNK-CONTIGUOUS B layout
// (B[t][kc][od][ki], kc=k/32, ki=k%32, via k_repack): a wave's per-chunk staging
// region (64 rows x 64B at chunk kc) is 4KB CONTIGUOUS -> each gload16 covers
// 8 fully-used 128B lines instead of 16 half-used (row stride was 2048B).
// Halves TA/L1 line transactions and doubles line utilization on the staging
// path, which the round-10 arithmetic identified as the wall. Data->LDS mapping
// and all arithmetic identical to v10 (pure global-address permutation).
// mode 0: Cb[r*128+o] = bf16(acc)   (rel: msg)
// mode 2: fout = lrelu(C[r,o] + acc) + trans[r,o]   (node + final fuse)
__global__ __launch_bounds__(256) void k_memgemm(
    const float* __restrict__ feat, const int* __restrict__ src,
    const float* __restrict__ coef, const bf16* __restrict__ B,
    float* __restrict__ C, bf16* __restrict__ Cb,
    const float* __restrict__ trans, float* __restrict__ fout,
    long srcStr, long coefStr, long Bstr, long CbStr,
    int Mvalid, int mode)
{
  __shared__ bf16 Af[64*136];       // stride 136 -> 2-way (free) bank aliasing
  __shared__ float cfS[8*64];       // [m][row]
  __shared__ bf16 Bs[3][4][2048];   // [ring][wave][4 groups x 16 rows x 32 k] (48 KB)
  int t = blockIdx.y;
  const int*   srcT  = src ? src + (size_t)t*srcStr : nullptr;
  const float* coefT = coef + (size_t)t*coefStr;
  const bf16*  Bt    = B + (size_t)t*Bstr;
  int tid = threadIdx.x, wave = tid >> 6, lane = tid & 63;
  int r0 = blockIdx.x * 64;

  // ---- stage 64 feat rows (fp32 -> bf16), 4 threads per row, coalesced ----
  {
    int rL = tid >> 2, seg = tid & 3;
    int r = r0 + rL;
    bool valid = r < Mvalid;
    int s = valid ? (srcT ? srcT[r] : r) : 0;
    const float4* fp = (const float4*)(feat + (size_t)s*128 + seg*32);
    bf16* ap = Af + rL*136 + seg*32;
    #pragma unroll
    for (int q=0;q<8;q+=2){
      float4 v0 = fp[q], v1 = fp[q+1];
      *(__hip_bfloat162*)(ap + q*4)     = __float22bfloat162_rn(make_float2(v0.x, v0.y));
      *(__hip_bfloat162*)(ap + q*4 + 2) = __float22bfloat162_rn(make_float2(v0.z, v0.w));
      *(__hip_bfloat162*)(ap + q*4 + 4) = __float22bfloat162_rn(make_float2(v1.x, v1.y));
      *(__hip_bfloat162*)(ap + q*4 + 6) = __float22bfloat162_rn(make_float2(v1.z, v1.w));
    }
  }
  // ---- stage coef transposed: cfS[m][r] ----
  if (tid < 64){
    int r = r0 + tid;
    bool valid = r < Mvalid;
    #pragma unroll
    for (int m=0;m<8;m++)
      cfS[m*64 + tid] = valid ? coefT[(size_t)r*8 + m] : 0.f;
  }

  int rq = lane >> 2;
  int cg = stage_cg(lane);
  int wm = (wave >> 1) * 32, wn = (wave & 1) * 64;
  int lm = lane & 15, lq = lane >> 4;
  int pc8 = read_pc8(lm, lq);

  // per-wave B base pointers, chunk-contiguous layout: addr = (kc*128 + od)*32 + ki
  const bf16* Bg0 = Bt + (size_t)(wn +  0 + rq)*32 + cg;
  const bf16* Bg1 = Bt + (size_t)(wn + 16 + rq)*32 + cg;
  const bf16* Bg2 = Bt + (size_t)(wn + 32 + rq)*32 + cg;
  const bf16* Bg3 = Bt + (size_t)(wn + 48 + rq)*32 + cg;

#define ISSUE_B(kk) do{                          \
    bf16* _d = &Bs[(kk)%3][wave][0];             \
    gload16(Bg0 + (kk)*4096, _d);                \
    gload16(Bg1 + (kk)*4096, _d + 512);          \
    gload16(Bg2 + (kk)*4096, _d + 1024);         \
    gload16(Bg3 + (kk)*4096, _d + 1536);         \
  }while(0)

  // ---- prologue: issue chunks 0,1 into private ring slots (8 loads in flight) ----
  ISSUE_B(0);
  ISSUE_B(1);

  // one barrier: Af/cfS ds_writes visible to all waves (B needs no cross-wave sync)
  asm volatile("s_waitcnt lgkmcnt(0)" ::: "memory");
  __builtin_amdgcn_s_barrier();

  // ---- A fragments LDS -> registers ONCE (reused for all m) ----
  short8 afr[4][2];
  #pragma unroll
  for (int ic=0; ic<4; ic++)
    #pragma unroll
    for (int i=0; i<2; i++)
      afr[ic][i] = *(const short8*)(Af + (size_t)(wm + i*16 + lm)*136 + ic*32 + lq*8);

  f32x4 accC[2][4];
  #pragma unroll
  for (int i=0;i<2;i++)
    #pragma unroll
    for (int j=0;j<4;j++) accC[i][j] = (f32x4){0.f,0.f,0.f,0.f};
  f32x4 accM[2][4];

  #pragma unroll
  for (int kk = 0; kk < 32; kk++){
    if (kk + 2 < 32) ISSUE_B(kk+2);
    // per-wave counted wait: oldest 4 (chunk kk's) retired when outstanding <= 8
    if (kk + 2 < 32)      asm volatile("s_waitcnt vmcnt(8)" ::: "memory");
    else if (kk + 1 < 32) asm volatile("s_waitcnt vmcnt(4)" ::: "memory");
    else                  asm volatile("s_waitcnt vmcnt(0)" ::: "memory");
    const int ic = kk & 3;
    const bf16* bb = &Bs[kk%3][wave][0];
    short8 bfv[4];
    #pragma unroll
    for (int j=0;j<4;j++)
      bfv[j] = *(const short8*)(bb + j*512 + lm*32 + pc8);
    if (ic == 0){
      #pragma unroll
      for (int i=0;i<2;i++)
        #pragma unroll
        for (int j=0;j<4;j++)
          accM[i][j] = __builtin_amdgcn_mfma_f32_16x16x32_bf16(afr[0][i], bfv[j],
                           (f32x4){0.f,0.f,0.f,0.f}, 0, 0, 0);
    } else {
      #pragma unroll
      for (int i=0;i<2;i++)
        #pragma unroll
        for (int j=0;j<4;j++)
          accM[i][j] = __builtin_amdgcn_mfma_f32_16x16x32_bf16(afr[ic][i], bfv[j], accM[i][j], 0, 0, 0);
    }
    // fold coef at C side after each m (= 4 chunks)
    if (ic == 3){
      const int m = kk >> 2;
      #pragma unroll
      for (int i=0;i<2;i++){
        f32x4 cf4 = *(const f32x4*)(cfS + m*64 + wm + i*16 + lq*4);
        #pragma unroll
        for (int j=0;j<4;j++)
          #pragma unroll
          for (int rg=0; rg<4; rg++)
            accC[i][j][rg] = fmaf(cf4[rg], accM[i][j][rg], accC[i][j][rg]);
      }
    }
  }
#undef ISSUE_B

  // epilogue
  #pragma unroll
  for (int i=0;i<2;i++){
    #pragma unroll
    for (int j=0;j<4;j++){
      int c = wn + j*16 + lm;
      #pragma unroll
      for (int rg=0; rg<4; rg++){
        int r = r0 + wm + i*16 + lq*4 + rg;
        if (r < Mvalid){
          float v = accC[i][j][rg];
          if (mode == 0){
            Cb[(size_t)t*CbStr + (size_t)r*128 + c] = __float2bfloat16(v);
          } else {
            float x = C[(size_t)r*128 + c] + v;
            x = x>0.f ? x : 0.2f*x;
            fout[(size_t)r*128 + c] = x + trans[(size_t)r*128 + c];
          }
        }
      }
    }
  }
}

// ---------- fp32 -> bf16 with zero pad ----------
__global__ void k_f2b(const float* __restrict__ in, bf16* __restrict__ o, int nv, int nt){
  int i = blockIdx.x*256 + threadIdx.x;
  if (i < nt) o[i] = __float2bfloat16(i < nv ? in[i] : 0.f);
}

// ---------- repack Ww (M,Do,Di) -> chunk-contiguous B [kc][od][ki] bf16, per slice ----------
// kc = (m*128+i)/32, ki = (m*128+i)%32. Wave's per-chunk staging region = 4KB contiguous.
__global__ void k_repack(const float* __restrict__ in, bf16* __restrict__ o){
  int s = blockIdx.y;
  int g = blockIdx.x*256 + threadIdx.x;          // g = m*16384 + od*128 + i
  int m = g >> 14, od = (g >> 7) & 127, i = g & 127;
  int k = m*128 + i;
  int kc = k >> 5, ki = k & 31;
  o[(size_t)s*131072 + ((size_t)kc*128 + od)*32 + ki] = __float2bfloat16(in[(size_t)s*131072 + g]);
}

// ---------- CSR build ----------
__global__ void k_hist(const int* __restrict__ dIdx, int* __restrict__ cnt, int E){
  int e = blockIdx.x*256+threadIdx.x;
  if (e<E) atomicAdd(&cnt[dIdx[e]], 1);
}

__global__ __launch_bounds__(1024) void k_scan(const int* __restrict__ in,
                                               int* __restrict__ out, int n){
  __shared__ int wsum[16];
  __shared__ int carry;
  int tidx = threadIdx.x, lane = tidx & 63, w = tidx >> 6;
  if (tidx == 0) carry = 0;
  __syncthreads();
  for (int base = 0; base < n; base += 1024){
    int i = base + tidx;
    int v = (i < n) ? in[i] : 0;
    int x = v;
    #pragma unroll
    for (int off = 1; off < 64; off <<= 1){
      int t = __shfl_up(x, off);
      if (lane >= off) x += t;
    }
    if (lane == 63) wsum[w] = x;
    __syncthreads();
    if (w == 0 && lane < 16){
      int t = wsum[lane];
      #pragma unroll
      for (int off=1; off<16; off<<=1){
        int u = __shfl_up(t, off, 16);
        if (lane >= off) t += u;
      }
      wsum[lane] = t;
    }
    __syncthreads();
    int woff = (w == 0) ? 0 : wsum[w-1];
    int excl = carry + woff + x - v;
    if (i < n) out[i] = excl;
    __syncthreads();
    if (tidx == 1023) carry = carry + wsum[15];
    __syncthreads();
  }
  if (tidx == 0) out[n] = carry;
}

__global__ void k_csr_scatter(const int* __restrict__ sIdx, const int* __restrict__ dIdx,
                              int sOff, const int* __restrict__ rowptr,
                              int* __restrict__ cursor, int* __restrict__ col, int E){
  int e = blockIdx.x*256+threadIdx.x; if (e>=E) return;
  int d = dIdx[e];
  int pos = rowptr[d] + atomicAdd(&cursor[d], 1);
  col[pos] = sIdx[e] + sOff;
}

__global__ void k_csr_scatter_eid(const int* __restrict__ dIdx, const int* __restrict__ rowptr,
                                  int* __restrict__ cursor, int* __restrict__ col, int E){
  int e = blockIdx.x*256+threadIdx.x; if (e>=E) return;
  int d = dIdx[e];
  int pos = rowptr[d] + atomicAdd(&cursor[d], 1);
  col[pos] = e;
}

// ------- fused GAT aggregation: online softmax + bf16 gather + rstb epilogue -------
// rstb[dl, c] = bf16(elu(softmax-weighted-sum + gb[c]))
__global__ __launch_bounds__(64) void k_gat_gather(
    const int* __restrict__ rowptr, const int* __restrict__ col,
    const float* __restrict__ el, const float* __restrict__ er,
    const bf16* __restrict__ Fb, const float* __restrict__ gb,
    bf16* __restrict__ rstb, int dOff)
{
  int dl = blockIdx.x;
  int lane = threadIdx.x;
  int h = lane >> 4;
  int off = (lane & 15) << 3;
  float erh = er[(size_t)(dl + dOff)*4 + h];
  float m = -INFINITY, den = 0.f;
  float acc[8];
  #pragma unroll
  for (int i=0;i<8;i++) acc[i]=0.f;
  int jb = rowptr[dl], je = rowptr[dl+1];
  for (int j=jb; j<je; j++){
    int s = col[j];
    float e = el[(size_t)s*4+h] + erh;
    e = e > 0.f ? e : 0.2f*e;
    float mn = fmaxf(m, e);
    float sc = __expf(m - mn);
    float wj = __expf(e - mn);
    den = den*sc + wj;
    m = mn;
    uint4 u = *(const uint4*)(Fb + (size_t)s*512 + h*128 + off);
    acc[0]=acc[0]*sc + wj*bu2f_lo(u.x); acc[1]=acc[1]*sc + wj*bu2f_hi(u.x);
    acc[2]=acc[2]*sc + wj*bu2f_lo(u.y); acc[3]=acc[3]*sc + wj*bu2f_hi(u.y);
    acc[4]=acc[4]*sc + wj*bu2f_lo(u.z); acc[5]=acc[5]*sc + wj*bu2f_hi(u.z);
    acc[6]=acc[6]*sc + wj*bu2f_lo(u.w); acc[7]=acc[7]*sc + wj*bu2f_hi(u.w);
  }
  float inv = den > 0.f ? 1.f/den : 0.f;
  int cb = h*128 + off;
  float x[8];
  #pragma unroll
  for (int q=0;q<8;q++){
    float v = acc[q]*inv + gb[cb+q];
    x[q] = v>0.f ? v : expm1f(v);
  }
  union { uint4 u; __hip_bfloat162 p[4]; } O;
  #pragma unroll
  for (int q=0;q<4;q++) O.p[q] = __float22bfloat162_rn(make_float2(x[2*q], x[2*q+1]));
  *(uint4*)(rstb + (size_t)dl*512 + cb) = O.u;
}

// ---------- coef / ncoef: lrelu(x @ Wc^T + bc), M=8 outputs ----------
// vectorized: float4 feat loads + transposed weight LDS (bitwise-identical FMA order)
__global__ void k_coef(const float* __restrict__ feat, const int* __restrict__ idx,
                       const float* __restrict__ Wc, const float* __restrict__ bc,
                       float* __restrict__ outc, int cnt){
  int t = blockIdx.y;
  __shared__ float wT[DD*MMEM];   // [d][m]
  __shared__ float bS[MMEM];
  for (int i=threadIdx.x;i<MMEM*DD;i+=128){
    int m = i >> 7, d = i & 127;
    wT[d*MMEM + m] = Wc[(size_t)t*MMEM*DD + i];
  }
  if (threadIdx.x < MMEM) bS[threadIdx.x] = bc[t*MMEM + threadIdx.x];
  __syncthreads();
  int e = blockIdx.x*128 + threadIdx.x; if (e >= cnt) return;
  int node = idx ? idx[(size_t)t*cnt + e] : e;
  float acc[MMEM];
  #pragma unroll
  for (int m=0;m<MMEM;m++) acc[m]=bS[m];
  const float4* fr = (const float4*)(feat + (size_t)node*DD);
  for (int d4=0; d4<32; d4++){
    float4 v = fr[d4];
    const float* w0 = wT + d4*4*MMEM;
    #pragma unroll
    for (int m=0;m<MMEM;m++) acc[m] = fmaf(v.x, w0[m], acc[m]);
    #pragma unroll
    for (int m=0;m<MMEM;m++) acc[m] = fmaf(v.y, w0[MMEM+m], acc[m]);
    #pragma unroll
    for (int m=0;m<MMEM;m++) acc[m] = fmaf(v.z, w0[2*MMEM+m], acc[m]);
    #pragma unroll
    for (int m=0;m<MMEM;m++) acc[m] = fmaf(v.w, w0[3*MMEM+m], acc[m]);
  }
  float* op = outc + ((size_t)t*cnt + e)*MMEM;
  #pragma unroll
  for (int m=0;m<MMEM;m++){ float v=acc[m]; op[m] = v>0.f ? v : 0.2f*v; }
}

// ---------- memory segment-sum gather (bf16 msg) ----------
__global__ void k_mem_gather(const int* __restrict__ rpT, const int* __restrict__ colT,
                             const bf16* __restrict__ msg, float* __restrict__ sAgg){
  int n = blockIdx.x*4 + (threadIdx.x >> 6);
  if (n >= NTOT) return;
  int lane = threadIdx.x & 63;
  int jb = rpT[n], je = rpT[n+1];
  float a0=0.f, a1=0.f;
  for (int j=jb;j<je;j++){
    unsigned u = ((const unsigned*)(msg + (size_t)colT[j]*128))[lane];
    a0 += bu2f_lo(u); a1 += bu2f_hi(u);
  }
  *(float2*)(sAgg + (size_t)n*128 + lane*2) = make_float2(a0, a1);
}

// ---------- memory LN ----------
__global__ void k_memln(const float* __restrict__ s, const int* __restrict__ rpT,
                        const float* __restrict__ lw, const float* __restrict__ lb,
                        const float* __restrict__ hb, float* __restrict__ outp){
  int n = blockIdx.x, lane = threadIdx.x;
  float c = fmaxf((float)(rpT[n+1]-rpT[n]), 1.f);
  float x1 = s[(size_t)n*128+lane]/c, x2 = s[(size_t)n*128+64+lane]/c;
  float t = x1+x2;
  #pragma unroll
  for (int off=32;off;off>>=1) t += __shfl_xor(t,off);
  float mu = t * (1.f/128.f);
  float d1=x1-mu, d2=x2-mu;
  float v = d1*d1+d2*d2;
  #pragma unroll
  for (int off=32;off;off>>=1) v += __shfl_xor(v,off);
  float r = rsqrtf(v*(1.f/128.f) + 1e-5f);
  outp[(size_t)n*128+lane]    = d1*r*lw[lane]    + lb[lane]    + hb[lane];
  outp[(size_t)n*128+64+lane] = d2*r*lw[64+lane] + lb[64+lane] + hb[64+lane];
}

// ---------- final LN over 384-wide concat ----------
__global__ void k_final_ln(const float* __restrict__ emb, const float* __restrict__ f1,
                           const float* __restrict__ f2, const float* __restrict__ w,
                           const float* __restrict__ b, float* __restrict__ out){
  int n = blockIdx.x, t = threadIdx.x;
  __shared__ float red[4];
  float x0 = emb[(size_t)n*128+t];
  float x1 = f1[(size_t)n*128+t];
  float x2 = f2[(size_t)n*128+t];
  float s = x0+x1+x2;
  #pragma unroll
  for (int off=32;off;off>>=1) s += __shfl_xor(s,off);
  if ((t&63)==0) red[t>>6] = s;
  __syncthreads();
  float mu = (red[0]+red[1]) * (1.f/384.f);
  float d0=x0-mu, d1=x1-mu, d2=x2-mu;
  float v = d0*d0+d1*d1+d2*d2;
  #pragma unroll
  for (int off=32;off;off>>=1) v += __shfl_xor(v,off);
  if ((t&63)==0) red[2+(t>>6)] = v;
  __syncthreads();
  float var = (red[2]+red[3]) * (1.f/384.f);
  float r = rsqrtf(var + 1e-5f);
  size_t o = (size_t)n*384;
  out[o+t]     = d0*r*w[t]     + b[t];
  out[o+128+t] = d1*r*w[128+t] + b[128+t];
  out[o+256+t] = d2*r*w[256+t] + b[256+t];
}

extern "C" void kernel_launch(void* const* d_in, const int* in_sizes, int n_in,
                              void* d_out, int out_size, void* d_ws, size_t ws_size,
                              hipStream_t stream)
{
  const float* emb   = (const float*)d_in[0];
  const float* fcW   = (const float*)d_in[1];
  const float* attl  = (const float*)d_in[2];
  const float* attr  = (const float*)d_in[3];
  const float* gbias = (const float*)d_in[4];
  const float* projW = (const float*)d_in[5];
  const float* projB = (const float*)d_in[6];
  const float* relWc = (const float*)d_in[7];
  const float* relbc = (const float*)d_in[8];
  const float* relWw = (const float*)d_in[9];
  const float* nodWc = (const float*)d_in[10];
  const float* nodbc = (const float*)d_in[11];
  const float* nodWw = (const float*)d_in[12];
  const float* hbias = (const float*)d_in[13];
  const float* mlnw  = (const float*)d_in[14];
  const float* mlnb  = (const float*)d_in[15];
  const float* flnw  = (const float*)d_in[16];
  const float* flnb  = (const float*)d_in[17];
  const int*  srcU  = (const int*)d_in[18];
  const int*  dstI  = (const int*)d_in[19];
  const int*  eSrc  = (const int*)d_in[20];
  const int*  eDst  = (const int*)d_in[21];
  float* out = (float*)d_out;

  char* wp = (char*)d_ws;
  auto alloc = [&](size_t bytes)->void* {
    void* p = (void*)wp; wp += (bytes + 511) & ~(size_t)511; return p;
  };
  float* feat1 = (float*)alloc((size_t)NTOT*DD*4);
  float* feat2 = (float*)alloc((size_t)NTOT*DD*4);
  float* Fbuf  = (float*)alloc((size_t)NTOT*512*4);         // overlay region (82 MB)
  float* rst   = (float*)alloc((size_t)NTOT*DD*2*4);        // sAgg + memO (41 MB)
  bf16*  rstb0 = (bf16*)alloc((size_t)2*MP_H*512*2);        // rstb dir0+dir1
  float* trans = (float*)alloc((size_t)NTOT*DD*4);
  float* elF   = (float*)alloc((size_t)NTOT*4*4);
  float* erF   = (float*)alloc((size_t)NTOT*4*4);
  int* rpA  = (int*)alloc((size_t)(NUSER+1)*4);
  int* colA = (int*)alloc((size_t)EUI*4);
  int* rpB  = (int*)alloc((size_t)(NITEM+1)*4);
  int* colB = (int*)alloc((size_t)EUI*4);
  int* icnt = (int*)alloc((size_t)20000*4);
  int* icur = (int*)alloc((size_t)20000*4);
  int* rpT  = (int*)alloc((size_t)(NTOT+1)*4);
  int* colT = (int*)alloc((size_t)TT*ET*4);
  int* cntT = (int*)alloc((size_t)NTOT*4);
  int* icurT= (int*)alloc((size_t)NTOT*4);
  bf16* featb  = (bf16*)alloc((size_t)MP_N*DD*2);
  bf16* fcWb   = (bf16*)alloc((size_t)4*512*DD*2);
  bf16* projWb = (bf16*)alloc((size_t)4*DD*512*2);
  bf16* relWwb = (bf16*)alloc((size_t)10*DD*1024*2);
  bf16* nodWwb = (bf16*)alloc((size_t)2*DD*1024*2);
  // overlays in Fbuf:
  bf16*  Fb     = (bf16*)Fbuf;                                    // NTOT*512 bf16 (41 MB)
  bf16*  msgBb  = (bf16*)((char*)Fbuf + (size_t)NTOT*512*2);      // 5*ET*128 bf16
  float* coefB  = (float*)((char*)msgBb + (size_t)TT*ET*128*2);   // 5*ET*8 fp32
  float* ncoefB = coefB + (size_t)TT*ET*8;                        // NTOT*8 fp32
  bf16*  rstb1  = rstb0 + (size_t)MP_H*512;
  float* sAgg   = rst;
  float* memO   = rst + (size_t)NTOT*DD;

  // ---- one-time: weight conversion/repack ----
  k_f2b<<<dim3((4*512*DD+255)/256),256,0,stream>>>(fcW, fcWb, 4*512*DD, 4*512*DD);
  k_f2b<<<dim3((4*DD*512+255)/256),256,0,stream>>>(projW, projWb, 4*DD*512, 4*DD*512);
  k_repack<<<dim3(512,10),256,0,stream>>>(relWw, relWwb);
  k_repack<<<dim3(512,2),256,0,stream>>>(nodWw, nodWwb);
  // zero rstb padding rows (re-poisoned every launch)
  hipMemsetAsync(rstb0 + (size_t)20000*512, 0, (size_t)(MP_H-20000)*512*2, stream);
  hipMemsetAsync(rstb1 + (size_t)20000*512, 0, (size_t)(MP_H-20000)*512*2, stream);

  // ---- one-time: CSR builds ----
  hipMemsetAsync(icnt, 0, 20000*4, stream);
  hipMemsetAsync(icur, 0, 20000*4, stream);
  k_hist<<<dim3((EUI+255)/256),256,0,stream>>>(srcU, icnt, EUI);
  k_scan<<<dim3(1),1024,0,stream>>>(icnt, rpA, NUSER);
  k_csr_scatter<<<dim3((EUI+255)/256),256,0,stream>>>(dstI, srcU, NUSER, rpA, icur, colA, EUI);
  hipMemsetAsync(icnt, 0, 20000*4, stream);
  hipMemsetAsync(icur, 0, 20000*4, stream);
  k_hist<<<dim3((EUI+255)/256),256,0,stream>>>(dstI, icnt, EUI);
  k_scan<<<dim3(1),1024,0,stream>>>(icnt, rpB, NITEM);
  k_csr_scatter<<<dim3((EUI+255)/256),256,0,stream>>>(srcU, dstI, 0, rpB, icur, colB, EUI);
  hipMemsetAsync(cntT, 0, NTOT*4, stream);
  hipMemsetAsync(icurT, 0, NTOT*4, stream);
  k_hist<<<dim3((TT*ET+255)/256),256,0,stream>>>(eDst, cntT, TT*ET);
  k_scan<<<dim3(1),1024,0,stream>>>(cntT, rpT, NTOT);
  k_csr_scatter_eid<<<dim3((TT*ET+255)/256),256,0,stream>>>(eDst, rpT, icurT, colT, TT*ET);

  const float* feats[3] = {emb, feat1, feat2};
  for (int l=0; l<2; l++){
    const float* fin  = feats[l];
    float* fout = (float*)feats[l+1];

    k_f2b<<<dim3((MP_N*DD+255)/256),256,0,stream>>>(fin, featb, NTOT*DD, MP_N*DD);

    for (int d=0; d<2; d++){
      // F = feat @ W^T fused with attn dots; bf16 F out
      k_fc_gemm<<<dim3(MP_N/128, 4),256,0,stream>>>(
          featb, fcWb + (size_t)(l*2+d)*512*DD, Fb,
          attl+(size_t)(l*2+d)*512, attr+(size_t)(l*2+d)*512, elF, erF, NTOT);
      int dOff = (d==0) ? 0 : NUSER;
      const int* rp  = (d==0) ? rpA : rpB;
      const int* col = (d==0) ? colA : colB;
      // gather fused with elu(rst+gbias) -> bf16
      k_gat_gather<<<dim3(20000),64,0,stream>>>(rp, col, elF, erF, Fb,
          gbias+(size_t)(l*2+d)*512, (d==0) ? rstb0 : rstb1, dOff);
    }
    // proj both directions in one dispatch: M=20000, N=128, K=512
    k_mfma_gemm<<<dim3(MP_H/128, 1, 2),256,0,stream>>>(
        rstb0, projWb + (size_t)(l*2)*DD*512, projB + (size_t)(l*2)*DD, trans,
        (long)MP_H*512, (long)DD*512, (long)DD, (long)20000*DD,
        DD, 20000, 512, 1, 0);

    // ---- memory layer ----
    k_coef<<<dim3((ET+127)/128, TT),128,0,stream>>>(fin, eDst,
        relWc+(size_t)l*TT*MMEM*DD, relbc+(size_t)l*TT*MMEM, coefB, ET);
    k_memgemm<<<dim3(ET/64, TT),256,0,stream>>>(
        fin, eSrc, coefB, relWwb + (size_t)l*TT*DD*1024,
        nullptr, msgBb, nullptr, nullptr,
        (long)ET, (long)ET*8, (long)DD*1024, (long)ET*128, ET, 0);
    k_mem_gather<<<dim3(NTOT/4),256,0,stream>>>(rpT, colT, msgBb, sAgg);
    k_memln<<<dim3(NTOT),64,0,stream>>>(sAgg, rpT, mlnw+(size_t)l*DD, mlnb+(size_t)l*DD,
                                        hbias+(size_t)l*DD, memO);
    k_coef<<<dim3((NTOT+127)/128, 1),128,0,stream>>>(fin, nullptr,
        nodWc+(size_t)l*MMEM*DD, nodbc+(size_t)l*MMEM, ncoefB, NTOT);
    // node memgemm fused with lrelu(memO+acc)+trans -> fout
    k_memgemm<<<dim3(MP_N/64, 1),256,0,stream>>>(
        fin, nullptr, ncoefB, nodWwb + (size_t)l*DD*1024,
        memO, nullptr, trans, fout,
        0, 0, 0, 0, NTOT, 2);
  }

  k_final_ln<<<dim3(NTOT),128,0,stream>>>(emb, feat1, feat2, flnw, flnb, out);
}